// Round 1
// baseline (408.764 us; speedup 1.0000x reference)
//
#include <hip/hip_runtime.h>
#include <math.h>

#define DD 64

// ---------------------------------------------------------------------------
// Xp = X @ W^T + b  (N x 64, K=64); also s_src = Xp@a_src, s_dst = Xp@a_dst.
// One wave per row: lane j owns output dim j. W staged in LDS (padded).
// ---------------------------------------------------------------------------
__global__ __launch_bounds__(256) void k_gemm(
    const float* __restrict__ X, const float* __restrict__ W,
    const float* __restrict__ bias, const float* __restrict__ a_src,
    const float* __restrict__ a_dst, float* __restrict__ Xp,
    float* __restrict__ s_src, float* __restrict__ s_dst, int N)
{
    __shared__ float wlds[DD][DD + 1];
    int t = threadIdx.x;
    for (int i = t; i < DD * DD; i += 256)
        wlds[i >> 6][i & 63] = W[i];
    __syncthreads();

    int lane = t & 63;
    float bj  = bias[lane];
    float asj = a_src[lane];
    float adj = a_dst[lane];

    int gw = (blockIdx.x * 256 + t) >> 6;
    int nw = (gridDim.x * 256) >> 6;
    for (int row = gw; row < N; row += nw) {
        float x = X[(size_t)row * DD + lane];
        float acc = bj;
        #pragma unroll
        for (int k = 0; k < DD; ++k)
            acc = fmaf(__shfl(x, k, 64), wlds[lane][k], acc);
        Xp[(size_t)row * DD + lane] = acc;

        float vs = acc * asj;
        float vd = acc * adj;
        #pragma unroll
        for (int off = 32; off; off >>= 1) {
            vs += __shfl_xor(vs, off, 64);
            vd += __shfl_xor(vd, off, 64);
        }
        if (lane == 0) { s_src[row] = vs; s_dst[row] = vd; }
    }
}

// ---------------------------------------------------------------------------
// Fused edge pass: score -> leaky_relu -> w=exp(score); accumulate
// denom[dst] += w  and  accG[dst][:] += w * Xp[src][:].
// Normalization (divide by denom) is deferred to the epilogue.
// One wave per edge, grid-stride.
// ---------------------------------------------------------------------------
__global__ __launch_bounds__(256) void k_edge(
    const int* __restrict__ e_src, const int* __restrict__ e_dst,
    const float* __restrict__ s_src, const float* __restrict__ s_dst,
    const float* __restrict__ Xp, float* __restrict__ accG,
    float* __restrict__ denom, int E)
{
    int lane = threadIdx.x & 63;
    int gw = (blockIdx.x * 256 + threadIdx.x) >> 6;
    int nw = (gridDim.x * 256) >> 6;
    for (int e = gw; e < E; e += nw) {
        int src = e_src[e], dst = e_dst[e];
        float s = s_src[src] + s_dst[dst];
        s = s > 0.f ? s : 0.2f * s;
        float w = __expf(s);
        if (lane == 0) unsafeAtomicAdd(&denom[dst], w);
        unsafeAtomicAdd(&accG[(size_t)dst * DD + lane],
                        w * Xp[(size_t)src * DD + lane]);
    }
}

// ---------------------------------------------------------------------------
// Hypergraph vertex/edge degree histograms (int atomics).
// ---------------------------------------------------------------------------
__global__ void k_deg(const int* __restrict__ inc_v, const int* __restrict__ inc_e,
                      int* __restrict__ dv, int* __restrict__ de, int P)
{
    int i = blockIdx.x * blockDim.x + threadIdx.x;
    if (i >= P) return;
    atomicAdd(&dv[inc_v[i]], 1);
    atomicAdd(&de[inc_e[i]], 1);
}

__global__ void k_invdeg(const int* __restrict__ dv, const int* __restrict__ de,
                         float* __restrict__ dvis, float* __restrict__ dein,
                         int N, int M)
{
    int i = blockIdx.x * blockDim.x + threadIdx.x;
    if (i < N) { int c = dv[i]; dvis[i] = c > 0 ? rsqrtf((float)c) : 0.f; }
    if (i < M) { int c = de[i]; dein[i] = c > 0 ? 1.f / (float)c : 0.f; }
}

// ---------------------------------------------------------------------------
// He[e][:] += Xp[v][:] * dv_isqrt[v]    (one wave per incidence pair)
// ---------------------------------------------------------------------------
__global__ __launch_bounds__(256) void k_he(
    const int* __restrict__ inc_v, const int* __restrict__ inc_e,
    const float* __restrict__ Xp, const float* __restrict__ dvis,
    float* __restrict__ He, int P)
{
    int lane = threadIdx.x & 63;
    int gw = (blockIdx.x * 256 + threadIdx.x) >> 6;
    int nw = (gridDim.x * 256) >> 6;
    for (int p = gw; p < P; p += nw) {
        int v = inc_v[p], e = inc_e[p];
        unsafeAtomicAdd(&He[(size_t)e * DD + lane],
                        Xp[(size_t)v * DD + lane] * dvis[v]);
    }
}

// ---------------------------------------------------------------------------
// accHG[v][:] += He[e][:] * de_inv[e] * dv_isqrt[v]   (accumulates into d_out)
// ---------------------------------------------------------------------------
__global__ __launch_bounds__(256) void k_xhg(
    const int* __restrict__ inc_v, const int* __restrict__ inc_e,
    const float* __restrict__ He, const float* __restrict__ dein,
    const float* __restrict__ dvis, float* __restrict__ accHG, int P)
{
    int lane = threadIdx.x & 63;
    int gw = (blockIdx.x * 256 + threadIdx.x) >> 6;
    int nw = (gridDim.x * 256) >> 6;
    for (int p = gw; p < P; p += nw) {
        int v = inc_v[p], e = inc_e[p];
        unsafeAtomicAdd(&accHG[(size_t)v * DD + lane],
                        He[(size_t)e * DD + lane] * dein[e] * dvis[v]);
    }
}

// ---------------------------------------------------------------------------
// out = elu(0.5 * (accG/denom + accHG));  accHG already lives in d_out.
// ---------------------------------------------------------------------------
__global__ void k_final(const float* __restrict__ accG,
                        const float* __restrict__ denom,
                        float* __restrict__ out, int total)
{
    int i = blockIdx.x * blockDim.x + threadIdx.x;
    if (i >= total) return;
    int n = i >> 6;
    float d = denom[n];
    float g = d > 0.f ? accG[i] / d : 0.f;
    float x = 0.5f * (g + out[i]);
    out[i] = x > 0.f ? x : expm1f(x);
}

extern "C" void kernel_launch(void* const* d_in, const int* in_sizes, int n_in,
                              void* d_out, int out_size, void* d_ws, size_t ws_size,
                              hipStream_t stream)
{
    const float* X     = (const float*)d_in[0];
    const float* W     = (const float*)d_in[1];
    const float* bias  = (const float*)d_in[2];
    const float* a_src = (const float*)d_in[3];
    const float* a_dst = (const float*)d_in[4];
    const int* e_src   = (const int*)d_in[5];
    const int* e_dst   = (const int*)d_in[6];
    const int* inc_v   = (const int*)d_in[7];
    const int* inc_e   = (const int*)d_in[8];
    float* out = (float*)d_out;

    const int N = in_sizes[0] / DD;   // 50000
    const int E = in_sizes[5];        // 800000
    const int P = in_sizes[7];        // 200000
    const int M = 10000;

    float* p = (float*)d_ws;
    float* Xp   = p; p += (size_t)N * DD;
    float* ssrc = p; p += N;
    float* sdst = p; p += N;
    float* dvis = p; p += N;
    float* dein = p; p += M;
    // --- zero-initialized region (contiguous, single memset) ---
    float* zstart = p;
    float* accG  = p; p += (size_t)N * DD;
    float* denom = p; p += N;
    int*   dv    = (int*)p; p += N;
    int*   de    = (int*)p; p += M;
    float* He    = p; p += (size_t)M * DD;
    size_t zbytes = (size_t)((char*)p - (char*)zstart);

    hipMemsetAsync(zstart, 0, zbytes, stream);
    hipMemsetAsync(out, 0, (size_t)N * DD * sizeof(float), stream);

    k_gemm<<<1024, 256, 0, stream>>>(X, W, bias, a_src, a_dst, Xp, ssrc, sdst, N);
    k_deg<<<(P + 255) / 256, 256, 0, stream>>>(inc_v, inc_e, dv, de, P);
    k_invdeg<<<(N + 255) / 256, 256, 0, stream>>>(dv, de, dvis, dein, N, M);
    k_edge<<<4096, 256, 0, stream>>>(e_src, e_dst, ssrc, sdst, Xp, accG, denom, E);
    k_he<<<2048, 256, 0, stream>>>(inc_v, inc_e, Xp, dvis, He, P);
    k_xhg<<<2048, 256, 0, stream>>>(inc_v, inc_e, He, dein, dvis, out, P);

    int total = N * DD;
    k_final<<<(total + 255) / 256, 256, 0, stream>>>(accG, denom, out, total);
}

// Round 2
// 368.699 us; speedup vs baseline: 1.1087x; 1.1087x over previous
//
#include <hip/hip_runtime.h>
#include <math.h>

#define DD 64

// ---------------------------------------------------------------------------
// Xp = X @ W^T + b  (N x 64, K=64); also s_src = Xp@a_src, s_dst = Xp@a_dst.
// One wave per row: lane j owns output dim j. W staged in LDS (padded).
// ---------------------------------------------------------------------------
__global__ __launch_bounds__(256) void k_gemm(
    const float* __restrict__ X, const float* __restrict__ W,
    const float* __restrict__ bias, const float* __restrict__ a_src,
    const float* __restrict__ a_dst, float* __restrict__ Xp,
    float* __restrict__ s_src, float* __restrict__ s_dst, int N)
{
    __shared__ float wlds[DD][DD + 1];
    int t = threadIdx.x;
    for (int i = t; i < DD * DD; i += 256)
        wlds[i >> 6][i & 63] = W[i];
    __syncthreads();

    int lane = t & 63;
    float bj  = bias[lane];
    float asj = a_src[lane];
    float adj = a_dst[lane];

    int gw = (blockIdx.x * 256 + t) >> 6;
    int nw = (gridDim.x * 256) >> 6;
    for (int row = gw; row < N; row += nw) {
        float x = X[(size_t)row * DD + lane];
        float acc = bj;
        #pragma unroll
        for (int k = 0; k < DD; ++k)
            acc = fmaf(__shfl(x, k, 64), wlds[lane][k], acc);
        Xp[(size_t)row * DD + lane] = acc;

        float vs = acc * asj;
        float vd = acc * adj;
        #pragma unroll
        for (int off = 32; off; off >>= 1) {
            vs += __shfl_xor(vs, off, 64);
            vd += __shfl_xor(vd, off, 64);
        }
        if (lane == 0) { s_src[row] = vs; s_dst[row] = vd; }
    }
}

// ---------------------------------------------------------------------------
// Degree histograms: deg_g[e_dst]++, dv[inc_v]++, de[inc_e]++ (int atomics).
// ---------------------------------------------------------------------------
__global__ void k_hist(const int* __restrict__ e_dst,
                       const int* __restrict__ inc_v, const int* __restrict__ inc_e,
                       int* __restrict__ deg_g, int* __restrict__ dv,
                       int* __restrict__ de, int E, int P)
{
    int i = blockIdx.x * blockDim.x + threadIdx.x;
    if (i < E) atomicAdd(&deg_g[e_dst[i]], 1);
    if (i < P) {
        atomicAdd(&dv[inc_v[i]], 1);
        atomicAdd(&de[inc_e[i]], 1);
    }
}

// ---------------------------------------------------------------------------
// Three independent exclusive scans (one per block): deg_g->start_g,
// dv->start_v (+dvis=rsqrt), de->start_e (+dein=1/c). Writes cursor copies.
// ---------------------------------------------------------------------------
__device__ void block_scan(const int* __restrict__ cnt, int len,
                           int* __restrict__ start, int* __restrict__ cursor,
                           float* __restrict__ inv, int mode)
{
    __shared__ int wtot[16];
    __shared__ int carry_s;
    int tid = threadIdx.x, lane = tid & 63, wid = tid >> 6;
    if (tid == 0) carry_s = 0;
    __syncthreads();
    for (int base = 0; base < len; base += 1024) {
        int i = base + tid;
        int v = (i < len) ? cnt[i] : 0;
        if (inv && i < len) {
            float c = (float)v;
            inv[i] = v > 0 ? (mode == 1 ? rsqrtf(c) : 1.0f / c) : 0.0f;
        }
        int incl = v;
        #pragma unroll
        for (int off = 1; off < 64; off <<= 1) {
            int tt = __shfl_up(incl, off, 64);
            if (lane >= off) incl += tt;
        }
        if (lane == 63) wtot[wid] = incl;
        __syncthreads();
        int carry = carry_s;
        int woff = 0;
        for (int wj = 0; wj < wid; ++wj) woff += wtot[wj];
        int excl = carry + woff + incl - v;
        if (i < len) { start[i] = excl; cursor[i] = excl; }
        __syncthreads();
        if (tid == 1023) carry_s = excl + v;
        __syncthreads();
    }
    if (tid == 0) start[len] = carry_s;
}

__global__ __launch_bounds__(1024) void k_scan(
    const int* __restrict__ deg_g, int* __restrict__ start_g, int* __restrict__ cur_g,
    const int* __restrict__ dv, int* __restrict__ start_v, int* __restrict__ cur_v,
    float* __restrict__ dvis,
    const int* __restrict__ de, int* __restrict__ start_e, int* __restrict__ cur_e,
    float* __restrict__ dein, int N, int M)
{
    if (blockIdx.x == 0)      block_scan(deg_g, N, start_g, cur_g, nullptr, 0);
    else if (blockIdx.x == 1) block_scan(dv,    N, start_v, cur_v, dvis, 1);
    else                      block_scan(de,    M, start_e, cur_e, dein, 2);
}

// ---------------------------------------------------------------------------
// Scatter into CSR slots. Edges: wsrc[pos] = (w, src) sorted by dst.
// Incidence: vsrt[pos] = (dvis[v], v) sorted by e;  e_sorted[pos] sorted by v.
// Only int position-atomics; no float atomics.
// ---------------------------------------------------------------------------
__global__ void k_scatter(const int* __restrict__ e_src, const int* __restrict__ e_dst,
                          const float* __restrict__ ssrc, const float* __restrict__ sdst,
                          int* __restrict__ cur_g, float2* __restrict__ wsrc,
                          const int* __restrict__ inc_v, const int* __restrict__ inc_e,
                          int* __restrict__ cur_v, int* __restrict__ cur_e,
                          float2* __restrict__ vsrt, int* __restrict__ e_sorted,
                          const float* __restrict__ dvis, int E, int P)
{
    int i = blockIdx.x * blockDim.x + threadIdx.x;
    if (i < E) {
        int s = e_src[i], d = e_dst[i];
        float sc = ssrc[s] + sdst[d];
        sc = sc > 0.f ? sc : 0.2f * sc;
        float w = __expf(sc);
        int pos = atomicAdd(&cur_g[d], 1);
        wsrc[pos] = make_float2(w, __int_as_float(s));
    }
    if (i < P) {
        int v = inc_v[i], e = inc_e[i];
        int p1 = atomicAdd(&cur_e[e], 1);
        vsrt[p1] = make_float2(dvis[v], __int_as_float(v));
        int p2 = atomicAdd(&cur_v[v], 1);
        e_sorted[p2] = e;
    }
}

// ---------------------------------------------------------------------------
// He_scaled[e][:] = dein[e] * sum_{v in seg} Xp[v][:] * dvis[v]. Wave per e.
// ---------------------------------------------------------------------------
__global__ __launch_bounds__(256) void k_he(
    const int* __restrict__ start_e, const float2* __restrict__ vsrt,
    const float* __restrict__ Xp, const float* __restrict__ dein,
    float* __restrict__ He, int M)
{
    int lane = threadIdx.x & 63;
    int e = (blockIdx.x * 256 + threadIdx.x) >> 6;
    if (e >= M) return;
    int s = start_e[e], t = start_e[e + 1];
    float acc = 0.f;
    for (int i = s; i < t; ++i) {
        float2 pv = vsrt[i];
        int v = __float_as_int(pv.y);
        acc += Xp[(size_t)v * DD + lane] * pv.x;
    }
    He[(size_t)e * DD + lane] = acc * dein[e];
}

// ---------------------------------------------------------------------------
// Per-node fused epilogue: gather GAT edges (sum w, sum w*Xp[src]) and
// hypergraph (sum He_scaled[e]); out = elu(0.5*(g/denom + dvis*hg)).
// One wave per node. Single coalesced write.
// ---------------------------------------------------------------------------
__global__ __launch_bounds__(256) void k_out(
    const int* __restrict__ start_g, const float2* __restrict__ wsrc,
    const int* __restrict__ start_v, const int* __restrict__ e_sorted,
    const float* __restrict__ Xp, const float* __restrict__ He,
    const float* __restrict__ dvis, float* __restrict__ out, int N)
{
    int lane = threadIdx.x & 63;
    int n = (blockIdx.x * 256 + threadIdx.x) >> 6;
    if (n >= N) return;

    int gs = start_g[n], ge = start_g[n + 1];
    float acc = 0.f, wsum = 0.f;
    for (int i = gs; i < ge; ++i) {
        float2 p = wsrc[i];
        int s = __float_as_int(p.y);
        wsum += p.x;
        acc = fmaf(p.x, Xp[(size_t)s * DD + lane], acc);
    }
    float g = (ge > gs) ? acc / wsum : 0.f;

    int vs = start_v[n], ve = start_v[n + 1];
    float hacc = 0.f;
    for (int i = vs; i < ve; ++i) {
        int e = e_sorted[i];
        hacc += He[(size_t)e * DD + lane];
    }
    float hg = dvis[n] * hacc;

    float x = 0.5f * (g + hg);
    out[(size_t)n * DD + lane] = x > 0.f ? x : expm1f(x);
}

extern "C" void kernel_launch(void* const* d_in, const int* in_sizes, int n_in,
                              void* d_out, int out_size, void* d_ws, size_t ws_size,
                              hipStream_t stream)
{
    const float* X     = (const float*)d_in[0];
    const float* W     = (const float*)d_in[1];
    const float* bias  = (const float*)d_in[2];
    const float* a_src = (const float*)d_in[3];
    const float* a_dst = (const float*)d_in[4];
    const int* e_src   = (const int*)d_in[5];
    const int* e_dst   = (const int*)d_in[6];
    const int* inc_v   = (const int*)d_in[7];
    const int* inc_e   = (const int*)d_in[8];
    float* out = (float*)d_out;

    const int N = in_sizes[0] / DD;   // 50000
    const int E = in_sizes[5];        // 800000
    const int P = in_sizes[7];        // 200000
    const int M = 10000;

    float* p = (float*)d_ws;
    float*  Xp      = p; p += (size_t)N * DD;      // even offsets kept for float2
    float2* wsrc    = (float2*)p; p += 2 * (size_t)E;
    float2* vsrt    = (float2*)p; p += 2 * (size_t)P;
    float*  He      = p; p += (size_t)M * DD;
    float*  ssrc    = p; p += N;
    float*  sdst    = p; p += N;
    float*  dvis    = p; p += N;
    float*  dein    = p; p += M;
    int*    e_sorted= (int*)p; p += P;
    int*    start_g = (int*)p; p += N + 2;
    int*    start_v = (int*)p; p += N + 2;
    int*    start_e = (int*)p; p += M + 2;
    int*    cur_g   = (int*)p; p += N;
    int*    cur_v   = (int*)p; p += N;
    int*    cur_e   = (int*)p; p += M;
    int*    deg_g   = (int*)p; p += N;   // ---- zero region start (deg_g)
    int*    dv      = (int*)p; p += N;
    int*    de      = (int*)p; p += M;

    hipMemsetAsync(deg_g, 0, (size_t)(2 * N + M) * sizeof(int), stream);

    k_gemm<<<1024, 256, 0, stream>>>(X, W, bias, a_src, a_dst, Xp, ssrc, sdst, N);
    k_hist<<<(E + 255) / 256, 256, 0, stream>>>(e_dst, inc_v, inc_e, deg_g, dv, de, E, P);
    k_scan<<<3, 1024, 0, stream>>>(deg_g, start_g, cur_g, dv, start_v, cur_v, dvis,
                                   de, start_e, cur_e, dein, N, M);
    k_scatter<<<(E + 255) / 256, 256, 0, stream>>>(e_src, e_dst, ssrc, sdst,
                                                   cur_g, wsrc, inc_v, inc_e,
                                                   cur_v, cur_e, vsrt, e_sorted,
                                                   dvis, E, P);
    k_he<<<(M * DD + 255) / 256, 256, 0, stream>>>(start_e, vsrt, Xp, dein, He, M);
    k_out<<<(N * DD + 255) / 256, 256, 0, stream>>>(start_g, wsrc, start_v, e_sorted,
                                                    Xp, He, dvis, out, N);
}

// Round 3
// 293.144 us; speedup vs baseline: 1.3944x; 1.2577x over previous
//
#include <hip/hip_runtime.h>
#include <math.h>

#define DD 64

__device__ __forceinline__ unsigned short f2bf(float x) {
    unsigned int u = __float_as_uint(x);
    u += 0x7fffu + ((u >> 16) & 1u);      // round-to-nearest-even
    return (unsigned short)(u >> 16);
}
__device__ __forceinline__ float bf2f(unsigned short h) {
    return __uint_as_float(((unsigned int)h) << 16);
}

// ---------------------------------------------------------------------------
// Xp_bf = bf16(X @ W^T + b); s_src = Xp@a_src, s_dst = Xp@a_dst (fp32).
// One wave per row: lane j owns output dim j.
// ---------------------------------------------------------------------------
__global__ __launch_bounds__(256) void k_gemm(
    const float* __restrict__ X, const float* __restrict__ W,
    const float* __restrict__ bias, const float* __restrict__ a_src,
    const float* __restrict__ a_dst, unsigned short* __restrict__ Xp_bf,
    float* __restrict__ s_src, float* __restrict__ s_dst, int N)
{
    __shared__ float wlds[DD][DD + 1];
    int t = threadIdx.x;
    for (int i = t; i < DD * DD; i += 256)
        wlds[i >> 6][i & 63] = W[i];
    __syncthreads();

    int lane = t & 63;
    float bj  = bias[lane];
    float asj = a_src[lane];
    float adj = a_dst[lane];

    int gw = (blockIdx.x * 256 + t) >> 6;
    int nw = (gridDim.x * 256) >> 6;
    for (int row = gw; row < N; row += nw) {
        float x = X[(size_t)row * DD + lane];
        float acc = bj;
        #pragma unroll
        for (int k = 0; k < DD; ++k)
            acc = fmaf(__shfl(x, k, 64), wlds[lane][k], acc);
        Xp_bf[(size_t)row * DD + lane] = f2bf(acc);

        float vs = acc * asj;
        float vd = acc * adj;
        #pragma unroll
        for (int off = 32; off; off >>= 1) {
            vs += __shfl_xor(vs, off, 64);
            vd += __shfl_xor(vd, off, 64);
        }
        if (lane == 0) { s_src[row] = vs; s_dst[row] = vd; }
    }
}

// ---------------------------------------------------------------------------
// Degree histograms (int atomics).
// ---------------------------------------------------------------------------
__global__ void k_hist(const int* __restrict__ e_dst,
                       const int* __restrict__ inc_v, const int* __restrict__ inc_e,
                       int* __restrict__ deg_g, int* __restrict__ dv,
                       int* __restrict__ de, int E, int P)
{
    int i = blockIdx.x * blockDim.x + threadIdx.x;
    if (i < E) atomicAdd(&deg_g[e_dst[i]], 1);
    if (i < P) {
        atomicAdd(&dv[inc_v[i]], 1);
        atomicAdd(&de[inc_e[i]], 1);
    }
}

// ---------------------------------------------------------------------------
// Exclusive scans, 4 elems/thread, one block each.
// ---------------------------------------------------------------------------
__device__ void block_scan4(const int* __restrict__ cnt, int len,
                            int* __restrict__ start, int* __restrict__ cursor,
                            float* __restrict__ inv, int mode)
{
    __shared__ int wtot[16];
    __shared__ int carry_s;
    int tid = threadIdx.x, lane = tid & 63, wid = tid >> 6;
    if (tid == 0) carry_s = 0;
    __syncthreads();
    for (int base = 0; base < len; base += 4096) {
        int i0 = base + tid * 4;
        int v[4];
        #pragma unroll
        for (int k = 0; k < 4; ++k) {
            int i = i0 + k;
            v[k] = (i < len) ? cnt[i] : 0;
            if (inv && i < len) {
                float c = (float)v[k];
                inv[i] = v[k] > 0 ? (mode == 1 ? rsqrtf(c) : 1.0f / c) : 0.0f;
            }
        }
        int s = v[0] + v[1] + v[2] + v[3];
        int incl = s;
        #pragma unroll
        for (int off = 1; off < 64; off <<= 1) {
            int tt = __shfl_up(incl, off, 64);
            if (lane >= off) incl += tt;
        }
        if (lane == 63) wtot[wid] = incl;
        __syncthreads();
        int carry = carry_s;
        int woff = 0;
        for (int wj = 0; wj < wid; ++wj) woff += wtot[wj];
        int excl = carry + woff + incl - s;
        int run = excl;
        #pragma unroll
        for (int k = 0; k < 4; ++k) {
            int i = i0 + k;
            if (i < len) { start[i] = run; cursor[i] = run; }
            run += v[k];
        }
        __syncthreads();
        if (tid == 1023) carry_s = excl + s;
        __syncthreads();
    }
    if (tid == 0) start[len] = carry_s;
}

__global__ __launch_bounds__(1024) void k_scan(
    const int* __restrict__ deg_g, int* __restrict__ start_g, int* __restrict__ cur_g,
    const int* __restrict__ dv, int* __restrict__ start_v, int* __restrict__ cur_v,
    float* __restrict__ dvis,
    const int* __restrict__ de, int* __restrict__ start_e, int* __restrict__ cur_e,
    float* __restrict__ dein, int N, int M)
{
    if (blockIdx.x == 0)      block_scan4(deg_g, N, start_g, cur_g, nullptr, 0);
    else if (blockIdx.x == 1) block_scan4(dv,    N, start_v, cur_v, dvis, 1);
    else                      block_scan4(de,    M, start_e, cur_e, dein, 2);
}

// ---------------------------------------------------------------------------
// Scatter indices into CSR slots (int position-atomics only).
// src_sorted: edge sources grouped by dst.
// v_sorted:   incidence vertices grouped by hyperedge.
// e_sorted:   incidence hyperedges grouped by vertex.
// ---------------------------------------------------------------------------
__global__ void k_scatter(const int* __restrict__ e_src, const int* __restrict__ e_dst,
                          int* __restrict__ cur_g, int* __restrict__ src_sorted,
                          const int* __restrict__ inc_v, const int* __restrict__ inc_e,
                          int* __restrict__ cur_v, int* __restrict__ cur_e,
                          int* __restrict__ v_sorted, int* __restrict__ e_sorted,
                          int E, int P)
{
    int i = blockIdx.x * blockDim.x + threadIdx.x;
    if (i < E) {
        int pos = atomicAdd(&cur_g[e_dst[i]], 1);
        src_sorted[pos] = e_src[i];
    }
    if (i < P) {
        int v = inc_v[i], e = inc_e[i];
        int p1 = atomicAdd(&cur_e[e], 1);
        v_sorted[p1] = v;
        int p2 = atomicAdd(&cur_v[v], 1);
        e_sorted[p2] = e;
    }
}

// ---------------------------------------------------------------------------
// He_bf[e][:] = bf16( dein[e] * sum_v Xp[v][:]*dvis[v] ).
// One wave per hyperedge; 4×16-lane groups keep 4 gathers in flight.
// ---------------------------------------------------------------------------
__global__ __launch_bounds__(256) void k_he(
    const int* __restrict__ start_e, const int* __restrict__ v_sorted,
    const unsigned short* __restrict__ Xp_bf, const float* __restrict__ dvis,
    const float* __restrict__ dein, unsigned short* __restrict__ He_bf, int M)
{
    int lane = threadIdx.x & 63;
    int grp = lane >> 4, gl = lane & 15;
    int e = (blockIdx.x * 256 + threadIdx.x) >> 6;
    if (e >= M) return;
    int s = start_e[e], t = start_e[e + 1];
    float a0 = 0.f, a1 = 0.f, a2 = 0.f, a3 = 0.f;
    for (int i = s + grp; i < t; i += 4) {
        int v = v_sorted[i];
        float dvv = dvis[v];
        ushort4 r = *(const ushort4*)(Xp_bf + (size_t)v * DD + gl * 4);
        a0 = fmaf(dvv, bf2f(r.x), a0);
        a1 = fmaf(dvv, bf2f(r.y), a1);
        a2 = fmaf(dvv, bf2f(r.z), a2);
        a3 = fmaf(dvv, bf2f(r.w), a3);
    }
    #pragma unroll
    for (int off = 16; off < 64; off <<= 1) {
        a0 += __shfl_xor(a0, off, 64);
        a1 += __shfl_xor(a1, off, 64);
        a2 += __shfl_xor(a2, off, 64);
        a3 += __shfl_xor(a3, off, 64);
    }
    if (grp == 0) {
        float din = dein[e];
        ushort4 o;
        o.x = f2bf(a0 * din); o.y = f2bf(a1 * din);
        o.z = f2bf(a2 * din); o.w = f2bf(a3 * din);
        *(ushort4*)(He_bf + (size_t)e * DD + gl * 4) = o;
    }
}

// ---------------------------------------------------------------------------
// Per-node fused epilogue: GAT gather (recompute w) + HG gather + ELU.
// One wave per node; 4×16-lane groups, ushort4 row loads.
// ---------------------------------------------------------------------------
__global__ __launch_bounds__(256) void k_out(
    const int* __restrict__ start_g, const int* __restrict__ src_sorted,
    const int* __restrict__ start_v, const int* __restrict__ e_sorted,
    const float* __restrict__ ssrc, const float* __restrict__ sdst,
    const unsigned short* __restrict__ Xp_bf, const unsigned short* __restrict__ He_bf,
    const float* __restrict__ dvis, float* __restrict__ out, int N)
{
    int lane = threadIdx.x & 63;
    int grp = lane >> 4, gl = lane & 15;
    int n = (blockIdx.x * 256 + threadIdx.x) >> 6;
    if (n >= N) return;

    float sd = sdst[n];
    int gs = start_g[n], ge = start_g[n + 1];
    float g0 = 0.f, g1 = 0.f, g2 = 0.f, g3 = 0.f, wsum = 0.f;
    for (int i = gs + grp; i < ge; i += 4) {
        int s = src_sorted[i];
        float sc = ssrc[s] + sd;
        sc = sc > 0.f ? sc : 0.2f * sc;
        float w = __expf(sc);
        wsum += w;
        ushort4 r = *(const ushort4*)(Xp_bf + (size_t)s * DD + gl * 4);
        g0 = fmaf(w, bf2f(r.x), g0);
        g1 = fmaf(w, bf2f(r.y), g1);
        g2 = fmaf(w, bf2f(r.z), g2);
        g3 = fmaf(w, bf2f(r.w), g3);
    }
    int vs = start_v[n], ve = start_v[n + 1];
    float h0 = 0.f, h1 = 0.f, h2 = 0.f, h3 = 0.f;
    for (int i = vs + grp; i < ve; i += 4) {
        int e = e_sorted[i];
        ushort4 r = *(const ushort4*)(He_bf + (size_t)e * DD + gl * 4);
        h0 += bf2f(r.x); h1 += bf2f(r.y); h2 += bf2f(r.z); h3 += bf2f(r.w);
    }
    #pragma unroll
    for (int off = 16; off < 64; off <<= 1) {
        g0 += __shfl_xor(g0, off, 64);
        g1 += __shfl_xor(g1, off, 64);
        g2 += __shfl_xor(g2, off, 64);
        g3 += __shfl_xor(g3, off, 64);
        h0 += __shfl_xor(h0, off, 64);
        h1 += __shfl_xor(h1, off, 64);
        h2 += __shfl_xor(h2, off, 64);
        h3 += __shfl_xor(h3, off, 64);
        wsum += __shfl_xor(wsum, off, 64);
    }
    if (grp == 0) {
        float winv = (ge > gs) ? 1.0f / wsum : 0.f;
        float dvn = dvis[n];
        float4 o;
        float x;
        x = 0.5f * (g0 * winv + dvn * h0); o.x = x > 0.f ? x : expm1f(x);
        x = 0.5f * (g1 * winv + dvn * h1); o.y = x > 0.f ? x : expm1f(x);
        x = 0.5f * (g2 * winv + dvn * h2); o.z = x > 0.f ? x : expm1f(x);
        x = 0.5f * (g3 * winv + dvn * h3); o.w = x > 0.f ? x : expm1f(x);
        *(float4*)(out + (size_t)n * DD + gl * 4) = o;
    }
}

extern "C" void kernel_launch(void* const* d_in, const int* in_sizes, int n_in,
                              void* d_out, int out_size, void* d_ws, size_t ws_size,
                              hipStream_t stream)
{
    const float* X     = (const float*)d_in[0];
    const float* W     = (const float*)d_in[1];
    const float* bias  = (const float*)d_in[2];
    const float* a_src = (const float*)d_in[3];
    const float* a_dst = (const float*)d_in[4];
    const int* e_src   = (const int*)d_in[5];
    const int* e_dst   = (const int*)d_in[6];
    const int* inc_v   = (const int*)d_in[7];
    const int* inc_e   = (const int*)d_in[8];
    float* out = (float*)d_out;

    const int N = in_sizes[0] / DD;   // 50000
    const int E = in_sizes[5];        // 800000
    const int P = in_sizes[7];        // 200000
    const int M = 10000;

    float* p = (float*)d_ws;
    unsigned short* Xp_bf = (unsigned short*)p; p += (size_t)N * DD / 2;
    unsigned short* He_bf = (unsigned short*)p; p += (size_t)M * DD / 2;
    int*    src_sorted = (int*)p; p += E;
    int*    v_sorted   = (int*)p; p += P;
    int*    e_sorted   = (int*)p; p += P;
    float*  ssrc    = p; p += N;
    float*  sdst    = p; p += N;
    float*  dvis    = p; p += N;
    float*  dein    = p; p += M;
    int*    start_g = (int*)p; p += N + 2;
    int*    start_v = (int*)p; p += N + 2;
    int*    start_e = (int*)p; p += M + 2;
    int*    cur_g   = (int*)p; p += N;
    int*    cur_v   = (int*)p; p += N;
    int*    cur_e   = (int*)p; p += M;
    int*    deg_g   = (int*)p; p += N;   // ---- zero region (deg_g, dv, de)
    int*    dv      = (int*)p; p += N;
    int*    de      = (int*)p; p += M;

    hipMemsetAsync(deg_g, 0, (size_t)(2 * N + M) * sizeof(int), stream);

    k_gemm<<<1024, 256, 0, stream>>>(X, W, bias, a_src, a_dst, Xp_bf, ssrc, sdst, N);
    k_hist<<<(E + 255) / 256, 256, 0, stream>>>(e_dst, inc_v, inc_e, deg_g, dv, de, E, P);
    k_scan<<<3, 1024, 0, stream>>>(deg_g, start_g, cur_g, dv, start_v, cur_v, dvis,
                                   de, start_e, cur_e, dein, N, M);
    k_scatter<<<(E + 255) / 256, 256, 0, stream>>>(e_src, e_dst, cur_g, src_sorted,
                                                   inc_v, inc_e, cur_v, cur_e,
                                                   v_sorted, e_sorted, E, P);
    k_he<<<(M * DD + 255) / 256, 256, 0, stream>>>(start_e, v_sorted, Xp_bf, dvis,
                                                   dein, He_bf, M);
    k_out<<<(N * DD + 255) / 256, 256, 0, stream>>>(start_g, src_sorted, start_v,
                                                    e_sorted, ssrc, sdst, Xp_bf,
                                                    He_bf, dvis, out, N);
}

// Round 4
// 152.159 us; speedup vs baseline: 2.6864x; 1.9266x over previous
//
#include <hip/hip_runtime.h>
#include <math.h>

#define DD 64

__device__ __forceinline__ unsigned short f2bf(float x) {
    unsigned int u = __float_as_uint(x);
    u += 0x7fffu + ((u >> 16) & 1u);      // round-to-nearest-even
    return (unsigned short)(u >> 16);
}
__device__ __forceinline__ float bflo(unsigned int u) { return __uint_as_float(u << 16); }
__device__ __forceinline__ float bfhi(unsigned int u) { return __uint_as_float(u & 0xffff0000u); }

// ---------------------------------------------------------------------------
// Xp_bf = bf16(X @ W^T + b); s_src = Xp@a_src, s_dst = Xp@a_dst (fp32).
// ---------------------------------------------------------------------------
__global__ __launch_bounds__(256) void k_gemm(
    const float* __restrict__ X, const float* __restrict__ W,
    const float* __restrict__ bias, const float* __restrict__ a_src,
    const float* __restrict__ a_dst, unsigned short* __restrict__ Xp_bf,
    float* __restrict__ s_src, float* __restrict__ s_dst, int N)
{
    __shared__ float wlds[DD][DD + 1];
    int t = threadIdx.x;
    for (int i = t; i < DD * DD; i += 256)
        wlds[i >> 6][i & 63] = W[i];
    __syncthreads();

    int lane = t & 63;
    float bj  = bias[lane];
    float asj = a_src[lane];
    float adj = a_dst[lane];

    int gw = (blockIdx.x * 256 + t) >> 6;
    int nw = (gridDim.x * 256) >> 6;
    for (int row = gw; row < N; row += nw) {
        float x = X[(size_t)row * DD + lane];
        float acc = bj;
        #pragma unroll
        for (int k = 0; k < DD; ++k)
            acc = fmaf(__shfl(x, k, 64), wlds[lane][k], acc);
        Xp_bf[(size_t)row * DD + lane] = f2bf(acc);

        float vs = acc * asj;
        float vd = acc * adj;
        #pragma unroll
        for (int off = 32; off; off >>= 1) {
            vs += __shfl_xor(vs, off, 64);
            vd += __shfl_xor(vd, off, 64);
        }
        if (lane == 0) { s_src[row] = vs; s_dst[row] = vd; }
    }
}

// ---------------------------------------------------------------------------
// Multisplit pass 1: per-(block,bucket) histograms for the 3 sort jobs.
// Job 0: e_dst (graph), 256 blocks.  Job 1: inc_e, 128.  Job 2: inc_v, 128.
// ---------------------------------------------------------------------------
__global__ __launch_bounds__(256) void k_count(
    const int* __restrict__ e_dst, const int* __restrict__ inc_e,
    const int* __restrict__ inc_v, int* __restrict__ hist_g,
    int* __restrict__ hist_ie, int* __restrict__ hist_iv,
    int E, int P, int N, int M)
{
    __shared__ int cnt[128];
    int b = blockIdx.x;
    const int* key; int n, B, SH, nblk, blk; int* hist;
    if (b < 256)      { key = e_dst; n = E; B = (N + 511) >> 9; SH = 9; nblk = 256; blk = b;       hist = hist_g;  }
    else if (b < 384) { key = inc_e; n = P; B = (M + 255) >> 8; SH = 8; nblk = 128; blk = b - 256; hist = hist_ie; }
    else              { key = inc_v; n = P; B = (N + 511) >> 9; SH = 9; nblk = 128; blk = b - 384; hist = hist_iv; }
    for (int i = threadIdx.x; i < B; i += 256) cnt[i] = 0;
    __syncthreads();
    int chunk = (n + nblk - 1) / nblk;
    int s = blk * chunk, e = min(n, s + chunk);
    for (int i = s + threadIdx.x; i < e; i += 256)
        atomicAdd(&cnt[key[i] >> SH], 1);
    __syncthreads();
    for (int i = threadIdx.x; i < B; i += 256)
        hist[i * nblk + blk] = cnt[i];
}

// ---------------------------------------------------------------------------
// In-place exclusive scan (one block, 1024 threads, 4 elems/thread).
// Writes total at a[len].
// ---------------------------------------------------------------------------
__device__ void block_scan4(int* a, int len)
{
    __shared__ int wtot[16];
    __shared__ int carry_s;
    int tid = threadIdx.x, lane = tid & 63, wid = tid >> 6;
    if (tid == 0) carry_s = 0;
    __syncthreads();
    for (int base = 0; base < len; base += 4096) {
        int i0 = base + tid * 4;
        int v[4];
        #pragma unroll
        for (int k = 0; k < 4; ++k) { int i = i0 + k; v[k] = (i < len) ? a[i] : 0; }
        int s = v[0] + v[1] + v[2] + v[3];
        int incl = s;
        #pragma unroll
        for (int off = 1; off < 64; off <<= 1) {
            int t = __shfl_up(incl, off, 64);
            if (lane >= off) incl += t;
        }
        if (lane == 63) wtot[wid] = incl;
        __syncthreads();
        int carry = carry_s;
        int woff = 0;
        for (int wj = 0; wj < wid; ++wj) woff += wtot[wj];
        int excl = carry + woff + incl - s;
        int run = excl;
        #pragma unroll
        for (int k = 0; k < 4; ++k) { int i = i0 + k; if (i < len) a[i] = run; run += v[k]; }
        __syncthreads();
        if (tid == 1023) carry_s = run;
        __syncthreads();
    }
    if (tid == 0) a[len] = carry_s;
}

__global__ __launch_bounds__(1024) void k_scan3(
    int* h0, int l0, int* h1, int l1, int* h2, int l2)
{
    if (blockIdx.x == 0)      block_scan4(h0, l0);
    else if (blockIdx.x == 1) block_scan4(h1, l1);
    else                      block_scan4(h2, l2);
}

// ---------------------------------------------------------------------------
// Multisplit pass 2: scatter (key,payload) into per-(block,bucket) private
// regions. LDS cursors, no global atomics, writes XCD-private.
// ---------------------------------------------------------------------------
__global__ __launch_bounds__(256) void k_scat(
    const int* __restrict__ e_dst, const int* __restrict__ e_src,
    const int* __restrict__ inc_e, const int* __restrict__ inc_v,
    const int* __restrict__ hist_g, const int* __restrict__ hist_ie,
    const int* __restrict__ hist_iv,
    int2* __restrict__ pg, int2* __restrict__ pie, int2* __restrict__ piv,
    int E, int P, int N, int M)
{
    __shared__ int cur[128];
    int b = blockIdx.x;
    const int *key, *pay, *base; int2* out;
    int n, B, SH, nblk, blk;
    if (b < 256)      { key = e_dst; pay = e_src; n = E; B = (N + 511) >> 9; SH = 9; nblk = 256; blk = b;       base = hist_g;  out = pg;  }
    else if (b < 384) { key = inc_e; pay = inc_v; n = P; B = (M + 255) >> 8; SH = 8; nblk = 128; blk = b - 256; base = hist_ie; out = pie; }
    else              { key = inc_v; pay = inc_e; n = P; B = (N + 511) >> 9; SH = 9; nblk = 128; blk = b - 384; base = hist_iv; out = piv; }
    for (int i = threadIdx.x; i < B; i += 256) cur[i] = base[i * nblk + blk];
    __syncthreads();
    int chunk = (n + nblk - 1) / nblk;
    int s = blk * chunk, e = min(n, s + chunk);
    for (int i = s + threadIdx.x; i < e; i += 256) {
        int k = key[i];
        int pos = atomicAdd(&cur[k >> SH], 1);
        out[pos] = make_int2(k, pay[i]);
    }
}

// ---------------------------------------------------------------------------
// Multisplit pass 3: per-bucket fine counting sort in LDS. Writes sorted
// payload (coalesced), start_* CSR offsets, and dvis/dein.
// ---------------------------------------------------------------------------
__global__ __launch_bounds__(256) void k_fine(
    const int* __restrict__ hist_g, const int* __restrict__ hist_ie,
    const int* __restrict__ hist_iv,
    const int2* __restrict__ pg, const int2* __restrict__ pie,
    const int2* __restrict__ piv,
    int* __restrict__ src_sorted, int* __restrict__ v_sorted,
    int* __restrict__ e_sorted,
    int* __restrict__ start_g, int* __restrict__ start_e,
    int* __restrict__ start_v,
    float* __restrict__ dein, float* __restrict__ dvis, int N, int M)
{
    __shared__ int lh[513];
    __shared__ int lc[512];
    __shared__ int lwt[4];
    __shared__ int lout[10240];
    int Bg = (N + 511) >> 9, Bie = (M + 255) >> 8;
    int b = blockIdx.x, tid = threadIdx.x;
    const int* base; const int2* pr; int* outp; int* startp; float* inv;
    int K, nblk, b0, NK, mode;
    if (b < Bg)            { base = hist_g;  pr = pg;  outp = src_sorted; startp = start_g; inv = nullptr; K = 512; nblk = 256; b0 = b;            NK = N; mode = 0; }
    else if (b < Bg + Bie) { base = hist_ie; pr = pie; outp = v_sorted;   startp = start_e; inv = dein;    K = 256; nblk = 128; b0 = b - Bg;       NK = M; mode = 2; }
    else                   { base = hist_iv; pr = piv; outp = e_sorted;   startp = start_v; inv = dvis;    K = 512; nblk = 128; b0 = b - Bg - Bie; NK = N; mode = 1; }

    int pbase = base[b0 * nblk], pend = base[(b0 + 1) * nblk];
    int cnt = pend - pbase;
    for (int i = tid; i < K; i += 256) { lh[i] = 0; lc[i] = 0; }
    __syncthreads();
    for (int i = tid; i < cnt; i += 256)
        atomicAdd(&lh[pr[pbase + i].x & (K - 1)], 1);
    __syncthreads();

    // exclusive scan of lh[0..K), total at lh[K]
    int per = K >> 8;                 // 1 or 2 elems per thread
    int i0 = tid * per;
    int a0 = lh[i0], a1 = (per == 2) ? lh[i0 + 1] : 0;
    int ssum = a0 + a1;
    int lane = tid & 63, wid = tid >> 6;
    int incl = ssum;
    #pragma unroll
    for (int off = 1; off < 64; off <<= 1) {
        int t = __shfl_up(incl, off, 64);
        if (lane >= off) incl += t;
    }
    if (lane == 63) lwt[wid] = incl;
    __syncthreads();
    int woff = 0;
    for (int wj = 0; wj < wid; ++wj) woff += lwt[wj];
    int excl = woff + incl - ssum;
    lh[i0] = excl;
    if (per == 2) lh[i0 + 1] = excl + a0;
    if (tid == 255) lh[K] = excl + ssum;
    __syncthreads();

    // scatter payloads into LDS at sorted positions
    for (int i = tid; i < cnt; i += 256) {
        int2 q = pr[pbase + i];
        int kl = q.x & (K - 1);
        int pos = lh[kl] + atomicAdd(&lc[kl], 1);
        lout[pos < 10240 ? pos : 10239] = q.y;
    }
    __syncthreads();
    for (int i = tid; i < cnt; i += 256)
        outp[pbase + i] = lout[i];
    for (int k = tid; k < K; k += 256) {
        int node = b0 * K + k;
        if (node < NK) {
            startp[node] = pbase + lh[k];
            if (mode) {
                int d = lh[k + 1] - lh[k];
                inv[node] = d > 0 ? (mode == 1 ? rsqrtf((float)d) : 1.0f / (float)d) : 0.0f;
            }
        }
    }
    int Bj = (NK + K - 1) / K;
    if (tid == 0 && b0 == Bj - 1) startp[NK] = pend;
}

// ---------------------------------------------------------------------------
// He_bf[e][:] = bf16( dein[e] * sum_v Xp[v][:]*dvis[v] ).
// Wave per hyperedge; 8×8-lane groups, uint4 (8 bf16) row loads.
// ---------------------------------------------------------------------------
__global__ __launch_bounds__(256, 8) void k_he(
    const int* __restrict__ start_e, const int* __restrict__ v_sorted,
    const unsigned short* __restrict__ Xp_bf, const float* __restrict__ dvis,
    const float* __restrict__ dein, unsigned short* __restrict__ He_bf, int M)
{
    int lane = threadIdx.x & 63, grp = lane >> 3, gl = lane & 7;
    int e = (blockIdx.x * 256 + threadIdx.x) >> 6;
    if (e >= M) return;
    int s = start_e[e], t = start_e[e + 1];
    float a[8] = {0.f, 0.f, 0.f, 0.f, 0.f, 0.f, 0.f, 0.f};
    for (int i = s + grp; i < t; i += 8) {
        int v = v_sorted[i];
        float dvv = dvis[v];
        uint4 r = *(const uint4*)(Xp_bf + (size_t)v * DD + gl * 8);
        a[0] = fmaf(dvv, bflo(r.x), a[0]); a[1] = fmaf(dvv, bfhi(r.x), a[1]);
        a[2] = fmaf(dvv, bflo(r.y), a[2]); a[3] = fmaf(dvv, bfhi(r.y), a[3]);
        a[4] = fmaf(dvv, bflo(r.z), a[4]); a[5] = fmaf(dvv, bfhi(r.z), a[5]);
        a[6] = fmaf(dvv, bflo(r.w), a[6]); a[7] = fmaf(dvv, bfhi(r.w), a[7]);
    }
    #pragma unroll
    for (int off = 8; off < 64; off <<= 1) {
        #pragma unroll
        for (int j = 0; j < 8; ++j) a[j] += __shfl_xor(a[j], off, 64);
    }
    if (grp == 0) {
        float din = dein[e];
        uint4 o;
        o.x = (unsigned)f2bf(a[0] * din) | ((unsigned)f2bf(a[1] * din) << 16);
        o.y = (unsigned)f2bf(a[2] * din) | ((unsigned)f2bf(a[3] * din) << 16);
        o.z = (unsigned)f2bf(a[4] * din) | ((unsigned)f2bf(a[5] * din) << 16);
        o.w = (unsigned)f2bf(a[6] * din) | ((unsigned)f2bf(a[7] * din) << 16);
        *(uint4*)(He_bf + (size_t)e * DD + gl * 8) = o;
    }
}

// ---------------------------------------------------------------------------
// Per-node fused epilogue: GAT gather (recompute w) + HG gather + ELU.
// Wave per node; 8×8-lane groups, uint4 row loads, full occupancy.
// ---------------------------------------------------------------------------
__global__ __launch_bounds__(256, 8) void k_out(
    const int* __restrict__ start_g, const int* __restrict__ src_sorted,
    const int* __restrict__ start_v, const int* __restrict__ e_sorted,
    const float* __restrict__ ssrc, const float* __restrict__ sdst,
    const unsigned short* __restrict__ Xp_bf, const unsigned short* __restrict__ He_bf,
    const float* __restrict__ dvis, float* __restrict__ out, int N)
{
    int lane = threadIdx.x & 63, grp = lane >> 3, gl = lane & 7;
    int n = (blockIdx.x * 256 + threadIdx.x) >> 6;
    if (n >= N) return;

    float sd = sdst[n];
    int gs = start_g[n], ge = start_g[n + 1];
    float g[8] = {0.f, 0.f, 0.f, 0.f, 0.f, 0.f, 0.f, 0.f};
    float wsum = 0.f;
    for (int i = gs + grp; i < ge; i += 8) {
        int s = src_sorted[i];
        float sc = ssrc[s] + sd;
        sc = sc > 0.f ? sc : 0.2f * sc;
        float w = __expf(sc);
        wsum += w;
        uint4 r = *(const uint4*)(Xp_bf + (size_t)s * DD + gl * 8);
        g[0] = fmaf(w, bflo(r.x), g[0]); g[1] = fmaf(w, bfhi(r.x), g[1]);
        g[2] = fmaf(w, bflo(r.y), g[2]); g[3] = fmaf(w, bfhi(r.y), g[3]);
        g[4] = fmaf(w, bflo(r.z), g[4]); g[5] = fmaf(w, bfhi(r.z), g[5]);
        g[6] = fmaf(w, bflo(r.w), g[6]); g[7] = fmaf(w, bfhi(r.w), g[7]);
    }
    int vs = start_v[n], ve = start_v[n + 1];
    float h[8] = {0.f, 0.f, 0.f, 0.f, 0.f, 0.f, 0.f, 0.f};
    for (int i = vs + grp; i < ve; i += 8) {
        int e = e_sorted[i];
        uint4 r = *(const uint4*)(He_bf + (size_t)e * DD + gl * 8);
        h[0] += bflo(r.x); h[1] += bfhi(r.x);
        h[2] += bflo(r.y); h[3] += bfhi(r.y);
        h[4] += bflo(r.z); h[5] += bfhi(r.z);
        h[6] += bflo(r.w); h[7] += bfhi(r.w);
    }
    #pragma unroll
    for (int off = 8; off < 64; off <<= 1) {
        #pragma unroll
        for (int j = 0; j < 8; ++j) {
            g[j] += __shfl_xor(g[j], off, 64);
            h[j] += __shfl_xor(h[j], off, 64);
        }
        wsum += __shfl_xor(wsum, off, 64);
    }
    if (grp == 0) {
        float winv = (ge > gs) ? 1.0f / wsum : 0.f;
        float dvn = dvis[n];
        float o[8];
        #pragma unroll
        for (int j = 0; j < 8; ++j) {
            float x = 0.5f * (g[j] * winv + dvn * h[j]);
            o[j] = x > 0.f ? x : expm1f(x);
        }
        float* op = out + (size_t)n * DD + gl * 8;
        *(float4*)op       = make_float4(o[0], o[1], o[2], o[3]);
        *(float4*)(op + 4) = make_float4(o[4], o[5], o[6], o[7]);
    }
}

extern "C" void kernel_launch(void* const* d_in, const int* in_sizes, int n_in,
                              void* d_out, int out_size, void* d_ws, size_t ws_size,
                              hipStream_t stream)
{
    const float* X     = (const float*)d_in[0];
    const float* W     = (const float*)d_in[1];
    const float* bias  = (const float*)d_in[2];
    const float* a_src = (const float*)d_in[3];
    const float* a_dst = (const float*)d_in[4];
    const int* e_src   = (const int*)d_in[5];
    const int* e_dst   = (const int*)d_in[6];
    const int* inc_v   = (const int*)d_in[7];
    const int* inc_e   = (const int*)d_in[8];
    float* out = (float*)d_out;

    const int N = in_sizes[0] / DD;   // 50000
    const int E = in_sizes[5];        // 800000
    const int P = in_sizes[7];        // 200000
    const int M = 10000;
    const int Bg = (N + 511) >> 9, Bie = (M + 255) >> 8, Biv = Bg;

    char* p = (char*)d_ws;
    unsigned short* Xp_bf = (unsigned short*)p; p += (size_t)N * DD * 2;
    unsigned short* He_bf = (unsigned short*)p; p += (size_t)M * DD * 2;
    int2* pg  = (int2*)p; p += (size_t)E * 8;
    int2* pie = (int2*)p; p += (size_t)P * 8;
    int2* piv = (int2*)p; p += (size_t)P * 8;
    int* src_sorted = (int*)p; p += (size_t)E * 4;
    int* v_sorted   = (int*)p; p += (size_t)P * 4;
    int* e_sorted   = (int*)p; p += (size_t)P * 4;
    float* ssrc = (float*)p; p += (size_t)N * 4;
    float* sdst = (float*)p; p += (size_t)N * 4;
    float* dvis = (float*)p; p += (size_t)N * 4;
    float* dein = (float*)p; p += (size_t)M * 4;
    int* start_g = (int*)p; p += (size_t)(N + 1) * 4;
    int* start_v = (int*)p; p += (size_t)(N + 1) * 4;
    int* start_e = (int*)p; p += (size_t)(M + 1) * 4;
    int* hist_g  = (int*)p; p += (size_t)(Bg * 256 + 1) * 4;
    int* hist_ie = (int*)p; p += (size_t)(Bie * 128 + 1) * 4;
    int* hist_iv = (int*)p; p += (size_t)(Biv * 128 + 1) * 4;

    k_gemm<<<1024, 256, 0, stream>>>(X, W, bias, a_src, a_dst, Xp_bf, ssrc, sdst, N);
    k_count<<<512, 256, 0, stream>>>(e_dst, inc_e, inc_v, hist_g, hist_ie, hist_iv,
                                     E, P, N, M);
    k_scan3<<<3, 1024, 0, stream>>>(hist_g, Bg * 256, hist_ie, Bie * 128,
                                    hist_iv, Biv * 128);
    k_scat<<<512, 256, 0, stream>>>(e_dst, e_src, inc_e, inc_v,
                                    hist_g, hist_ie, hist_iv, pg, pie, piv,
                                    E, P, N, M);
    k_fine<<<Bg + Bie + Biv, 256, 0, stream>>>(hist_g, hist_ie, hist_iv, pg, pie, piv,
                                               src_sorted, v_sorted, e_sorted,
                                               start_g, start_e, start_v,
                                               dein, dvis, N, M);
    k_he<<<(M * DD + 255) / 256, 256, 0, stream>>>(start_e, v_sorted, Xp_bf, dvis,
                                                   dein, He_bf, M);
    k_out<<<(N * DD + 255) / 256, 256, 0, stream>>>(start_g, src_sorted, start_v,
                                                    e_sorted, ssrc, sdst, Xp_bf,
                                                    He_bf, dvis, out, N);
}

// Round 5
// 117.285 us; speedup vs baseline: 3.4852x; 1.2973x over previous
//
#include <hip/hip_runtime.h>
#include <math.h>

#define DD 64

typedef __attribute__((ext_vector_type(8))) short bf16x8;
typedef __attribute__((ext_vector_type(4))) float f32x4;

__device__ __forceinline__ unsigned short f2bf(float x) {
    unsigned int u = __float_as_uint(x);
    u += 0x7fffu + ((u >> 16) & 1u);      // round-to-nearest-even
    return (unsigned short)(u >> 16);
}
__device__ __forceinline__ float bflo(unsigned int u) { return __uint_as_float(u << 16); }
__device__ __forceinline__ float bfhi(unsigned int u) { return __uint_as_float(u & 0xffff0000u); }

// ---------------------------------------------------------------------------
// MFMA GEMM: Xp_bf = bf16(X @ W^T + b); s_src = Xp@a_src, s_dst = Xp@a_dst.
// One 16-row x 64-col tile per wave per iteration (K=64 -> 8 MFMAs).
// A/B lane map: m|n = lane&15, k = (lane>>4)*8 + e.  D: n=lane&15,
// m = (lane>>4)*4 + reg.  W/bias/a fragments hoisted before the tile loop.
// ---------------------------------------------------------------------------
__global__ __launch_bounds__(256) void k_gemm(
    const float* __restrict__ X, const float* __restrict__ W,
    const float* __restrict__ bias, const float* __restrict__ a_src,
    const float* __restrict__ a_dst, unsigned short* __restrict__ Xp_bf,
    float* __restrict__ s_src, float* __restrict__ s_dst, int N)
{
    int t = threadIdx.x;
    int lane = t & 63;
    int col = lane & 15;      // n within 16-col tile
    int kq  = lane >> 4;      // k-quarter / D row-group
    int rowbase = kq * 4;

    // B fragments: 4 col-tiles x 2 k-steps; elem e = W[j][ks*32+kq*8+e]
    bf16x8 bfrag[4][2];
    float bj[4], asr[4], adr[4];
    #pragma unroll
    for (int jt = 0; jt < 4; ++jt) {
        int j = jt * 16 + col;
        #pragma unroll
        for (int ks = 0; ks < 2; ++ks) {
            const float* wp = W + j * DD + ks * 32 + kq * 8;
            float4 w0 = *(const float4*)wp;
            float4 w1 = *(const float4*)(wp + 4);
            bf16x8 bb;
            bb[0] = (short)f2bf(w0.x); bb[1] = (short)f2bf(w0.y);
            bb[2] = (short)f2bf(w0.z); bb[3] = (short)f2bf(w0.w);
            bb[4] = (short)f2bf(w1.x); bb[5] = (short)f2bf(w1.y);
            bb[6] = (short)f2bf(w1.z); bb[7] = (short)f2bf(w1.w);
            bfrag[jt][ks] = bb;
        }
        bj[jt]  = bias[j];
        asr[jt] = a_src[j];
        adr[jt] = a_dst[j];
    }

    int wave  = (blockIdx.x * 256 + t) >> 6;
    int nwave = (gridDim.x * 256) >> 6;
    int ntiles = (N + 15) >> 4;
    for (int tile = wave; tile < ntiles; tile += nwave) {
        int r0 = tile * 16;
        int rl = r0 + col;                 // A-row this lane loads
        if (rl >= N) rl = N - 1;
        const float* xp = X + (size_t)rl * DD + kq * 8;
        float4 x0 = *(const float4*)xp;
        float4 x1 = *(const float4*)(xp + 4);
        float4 x2 = *(const float4*)(xp + 32);
        float4 x3 = *(const float4*)(xp + 36);
        bf16x8 a0, a1;
        a0[0] = (short)f2bf(x0.x); a0[1] = (short)f2bf(x0.y);
        a0[2] = (short)f2bf(x0.z); a0[3] = (short)f2bf(x0.w);
        a0[4] = (short)f2bf(x1.x); a0[5] = (short)f2bf(x1.y);
        a0[6] = (short)f2bf(x1.z); a0[7] = (short)f2bf(x1.w);
        a1[0] = (short)f2bf(x2.x); a1[1] = (short)f2bf(x2.y);
        a1[2] = (short)f2bf(x2.z); a1[3] = (short)f2bf(x2.w);
        a1[4] = (short)f2bf(x3.x); a1[5] = (short)f2bf(x3.y);
        a1[6] = (short)f2bf(x3.z); a1[7] = (short)f2bf(x3.w);

        f32x4 acc[4];
        #pragma unroll
        for (int jt = 0; jt < 4; ++jt) {
            f32x4 c = {bj[jt], bj[jt], bj[jt], bj[jt]};
            c = __builtin_amdgcn_mfma_f32_16x16x32_bf16(a0, bfrag[jt][0], c, 0, 0, 0);
            c = __builtin_amdgcn_mfma_f32_16x16x32_bf16(a1, bfrag[jt][1], c, 0, 0, 0);
            acc[jt] = c;
        }

        int orow = r0 + rowbase;
        #pragma unroll
        for (int jt = 0; jt < 4; ++jt) {
            #pragma unroll
            for (int r = 0; r < 4; ++r) {
                int rr = orow + r;
                if (rr < N)
                    Xp_bf[(size_t)rr * DD + jt * 16 + col] = f2bf(acc[jt][r]);
            }
        }

        float vs[4], vd[4];
        #pragma unroll
        for (int r = 0; r < 4; ++r) {
            vs[r] = acc[0][r] * asr[0] + acc[1][r] * asr[1]
                  + acc[2][r] * asr[2] + acc[3][r] * asr[3];
            vd[r] = acc[0][r] * adr[0] + acc[1][r] * adr[1]
                  + acc[2][r] * adr[2] + acc[3][r] * adr[3];
        }
        #pragma unroll
        for (int off = 1; off < 16; off <<= 1) {
            #pragma unroll
            for (int r = 0; r < 4; ++r) {
                vs[r] += __shfl_xor(vs[r], off, 64);
                vd[r] += __shfl_xor(vd[r], off, 64);
            }
        }
        if (col == 0) {
            #pragma unroll
            for (int r = 0; r < 4; ++r) {
                int rr = orow + r;
                if (rr < N) { s_src[rr] = vs[r]; s_dst[rr] = vd[r]; }
            }
        }
    }
}

// ---------------------------------------------------------------------------
// Multisplit pass 1: per-(block,bucket) histograms for the 3 sort jobs.
// ---------------------------------------------------------------------------
__global__ __launch_bounds__(256) void k_count(
    const int* __restrict__ e_dst, const int* __restrict__ inc_e,
    const int* __restrict__ inc_v, int* __restrict__ hist_g,
    int* __restrict__ hist_ie, int* __restrict__ hist_iv,
    int E, int P, int N, int M)
{
    __shared__ int cnt[128];
    int b = blockIdx.x;
    const int* key; int n, B, SH, nblk, blk; int* hist;
    if (b < 256)      { key = e_dst; n = E; B = (N + 511) >> 9; SH = 9; nblk = 256; blk = b;       hist = hist_g;  }
    else if (b < 384) { key = inc_e; n = P; B = (M + 255) >> 8; SH = 8; nblk = 128; blk = b - 256; hist = hist_ie; }
    else              { key = inc_v; n = P; B = (N + 511) >> 9; SH = 9; nblk = 128; blk = b - 384; hist = hist_iv; }
    for (int i = threadIdx.x; i < B; i += 256) cnt[i] = 0;
    __syncthreads();
    int chunk = (n + nblk - 1) / nblk;
    int s = blk * chunk, e = min(n, s + chunk);
    for (int i = s + threadIdx.x; i < e; i += 256)
        atomicAdd(&cnt[key[i] >> SH], 1);
    __syncthreads();
    for (int i = threadIdx.x; i < B; i += 256)
        hist[i * nblk + blk] = cnt[i];
}

// ---------------------------------------------------------------------------
// In-place exclusive scan (one block, 1024 threads, 4 elems/thread).
// ---------------------------------------------------------------------------
__device__ void block_scan4(int* a, int len)
{
    __shared__ int wtot[16];
    __shared__ int carry_s;
    int tid = threadIdx.x, lane = tid & 63, wid = tid >> 6;
    if (tid == 0) carry_s = 0;
    __syncthreads();
    for (int base = 0; base < len; base += 4096) {
        int i0 = base + tid * 4;
        int v[4];
        #pragma unroll
        for (int k = 0; k < 4; ++k) { int i = i0 + k; v[k] = (i < len) ? a[i] : 0; }
        int s = v[0] + v[1] + v[2] + v[3];
        int incl = s;
        #pragma unroll
        for (int off = 1; off < 64; off <<= 1) {
            int t = __shfl_up(incl, off, 64);
            if (lane >= off) incl += t;
        }
        if (lane == 63) wtot[wid] = incl;
        __syncthreads();
        int carry = carry_s;
        int woff = 0;
        for (int wj = 0; wj < wid; ++wj) woff += wtot[wj];
        int excl = carry + woff + incl - s;
        int run = excl;
        #pragma unroll
        for (int k = 0; k < 4; ++k) { int i = i0 + k; if (i < len) a[i] = run; run += v[k]; }
        __syncthreads();
        if (tid == 1023) carry_s = run;
        __syncthreads();
    }
    if (tid == 0) a[len] = carry_s;
}

__global__ __launch_bounds__(1024) void k_scan3(
    int* h0, int l0, int* h1, int l1, int* h2, int l2)
{
    if (blockIdx.x == 0)      block_scan4(h0, l0);
    else if (blockIdx.x == 1) block_scan4(h1, l1);
    else                      block_scan4(h2, l2);
}

// ---------------------------------------------------------------------------
// Multisplit pass 2: scatter (key,payload) into per-(block,bucket) regions.
// ---------------------------------------------------------------------------
__global__ __launch_bounds__(256) void k_scat(
    const int* __restrict__ e_dst, const int* __restrict__ e_src,
    const int* __restrict__ inc_e, const int* __restrict__ inc_v,
    const int* __restrict__ hist_g, const int* __restrict__ hist_ie,
    const int* __restrict__ hist_iv,
    int2* __restrict__ pg, int2* __restrict__ pie, int2* __restrict__ piv,
    int E, int P, int N, int M)
{
    __shared__ int cur[128];
    int b = blockIdx.x;
    const int *key, *pay, *base; int2* out;
    int n, B, SH, nblk, blk;
    if (b < 256)      { key = e_dst; pay = e_src; n = E; B = (N + 511) >> 9; SH = 9; nblk = 256; blk = b;       base = hist_g;  out = pg;  }
    else if (b < 384) { key = inc_e; pay = inc_v; n = P; B = (M + 255) >> 8; SH = 8; nblk = 128; blk = b - 256; base = hist_ie; out = pie; }
    else              { key = inc_v; pay = inc_e; n = P; B = (N + 511) >> 9; SH = 9; nblk = 128; blk = b - 384; base = hist_iv; out = piv; }
    for (int i = threadIdx.x; i < B; i += 256) cur[i] = base[i * nblk + blk];
    __syncthreads();
    int chunk = (n + nblk - 1) / nblk;
    int s = blk * chunk, e = min(n, s + chunk);
    for (int i = s + threadIdx.x; i < e; i += 256) {
        int k = key[i];
        int pos = atomicAdd(&cur[k >> SH], 1);
        out[pos] = make_int2(k, pay[i]);
    }
}

// ---------------------------------------------------------------------------
// Multisplit pass 3: per-bucket fine counting sort in LDS.
// ---------------------------------------------------------------------------
__global__ __launch_bounds__(256) void k_fine(
    const int* __restrict__ hist_g, const int* __restrict__ hist_ie,
    const int* __restrict__ hist_iv,
    const int2* __restrict__ pg, const int2* __restrict__ pie,
    const int2* __restrict__ piv,
    int* __restrict__ src_sorted, int* __restrict__ v_sorted,
    int* __restrict__ e_sorted,
    int* __restrict__ start_g, int* __restrict__ start_e,
    int* __restrict__ start_v,
    float* __restrict__ dein, float* __restrict__ dvis, int N, int M)
{
    __shared__ int lh[513];
    __shared__ int lc[512];
    __shared__ int lwt[4];
    __shared__ int lout[10240];
    int Bg = (N + 511) >> 9, Bie = (M + 255) >> 8;
    int b = blockIdx.x, tid = threadIdx.x;
    const int* base; const int2* pr; int* outp; int* startp; float* inv;
    int K, nblk, b0, NK, mode;
    if (b < Bg)            { base = hist_g;  pr = pg;  outp = src_sorted; startp = start_g; inv = nullptr; K = 512; nblk = 256; b0 = b;            NK = N; mode = 0; }
    else if (b < Bg + Bie) { base = hist_ie; pr = pie; outp = v_sorted;   startp = start_e; inv = dein;    K = 256; nblk = 128; b0 = b - Bg;       NK = M; mode = 2; }
    else                   { base = hist_iv; pr = piv; outp = e_sorted;   startp = start_v; inv = dvis;    K = 512; nblk = 128; b0 = b - Bg - Bie; NK = N; mode = 1; }

    int pbase = base[b0 * nblk], pend = base[(b0 + 1) * nblk];
    int cnt = pend - pbase;
    for (int i = tid; i < K; i += 256) { lh[i] = 0; lc[i] = 0; }
    __syncthreads();
    for (int i = tid; i < cnt; i += 256)
        atomicAdd(&lh[pr[pbase + i].x & (K - 1)], 1);
    __syncthreads();

    int per = K >> 8;
    int i0 = tid * per;
    int a0 = lh[i0], a1 = (per == 2) ? lh[i0 + 1] : 0;
    int ssum = a0 + a1;
    int lane = tid & 63, wid = tid >> 6;
    int incl = ssum;
    #pragma unroll
    for (int off = 1; off < 64; off <<= 1) {
        int t = __shfl_up(incl, off, 64);
        if (lane >= off) incl += t;
    }
    if (lane == 63) lwt[wid] = incl;
    __syncthreads();
    int woff = 0;
    for (int wj = 0; wj < wid; ++wj) woff += lwt[wj];
    int excl = woff + incl - ssum;
    lh[i0] = excl;
    if (per == 2) lh[i0 + 1] = excl + a0;
    if (tid == 255) lh[K] = excl + ssum;
    __syncthreads();

    for (int i = tid; i < cnt; i += 256) {
        int2 q = pr[pbase + i];
        int kl = q.x & (K - 1);
        int pos = lh[kl] + atomicAdd(&lc[kl], 1);
        lout[pos < 10240 ? pos : 10239] = q.y;
    }
    __syncthreads();
    for (int i = tid; i < cnt; i += 256)
        outp[pbase + i] = lout[i];
    for (int k = tid; k < K; k += 256) {
        int node = b0 * K + k;
        if (node < NK) {
            startp[node] = pbase + lh[k];
            if (mode) {
                int d = lh[k + 1] - lh[k];
                inv[node] = d > 0 ? (mode == 1 ? rsqrtf((float)d) : 1.0f / (float)d) : 0.0f;
            }
        }
    }
    int Bj = (NK + K - 1) / K;
    if (tid == 0 && b0 == Bj - 1) startp[NK] = pend;
}

// ---------------------------------------------------------------------------
// He_bf[e][:] = bf16( dein[e] * sum_v Xp[v][:]*dvis[v] ).
// ---------------------------------------------------------------------------
__global__ __launch_bounds__(256, 8) void k_he(
    const int* __restrict__ start_e, const int* __restrict__ v_sorted,
    const unsigned short* __restrict__ Xp_bf, const float* __restrict__ dvis,
    const float* __restrict__ dein, unsigned short* __restrict__ He_bf, int M)
{
    int lane = threadIdx.x & 63, grp = lane >> 3, gl = lane & 7;
    int e = (blockIdx.x * 256 + threadIdx.x) >> 6;
    if (e >= M) return;
    int s = start_e[e], t = start_e[e + 1];
    float a[8] = {0.f, 0.f, 0.f, 0.f, 0.f, 0.f, 0.f, 0.f};
    for (int i = s + grp; i < t; i += 8) {
        int v = v_sorted[i];
        float dvv = dvis[v];
        uint4 r = *(const uint4*)(Xp_bf + (size_t)v * DD + gl * 8);
        a[0] = fmaf(dvv, bflo(r.x), a[0]); a[1] = fmaf(dvv, bfhi(r.x), a[1]);
        a[2] = fmaf(dvv, bflo(r.y), a[2]); a[3] = fmaf(dvv, bfhi(r.y), a[3]);
        a[4] = fmaf(dvv, bflo(r.z), a[4]); a[5] = fmaf(dvv, bfhi(r.z), a[5]);
        a[6] = fmaf(dvv, bflo(r.w), a[6]); a[7] = fmaf(dvv, bfhi(r.w), a[7]);
    }
    #pragma unroll
    for (int off = 8; off < 64; off <<= 1) {
        #pragma unroll
        for (int j = 0; j < 8; ++j) a[j] += __shfl_xor(a[j], off, 64);
    }
    if (grp == 0) {
        float din = dein[e];
        uint4 o;
        o.x = (unsigned)f2bf(a[0] * din) | ((unsigned)f2bf(a[1] * din) << 16);
        o.y = (unsigned)f2bf(a[2] * din) | ((unsigned)f2bf(a[3] * din) << 16);
        o.z = (unsigned)f2bf(a[4] * din) | ((unsigned)f2bf(a[5] * din) << 16);
        o.w = (unsigned)f2bf(a[6] * din) | ((unsigned)f2bf(a[7] * din) << 16);
        *(uint4*)(He_bf + (size_t)e * DD + gl * 8) = o;
    }
}

// ---------------------------------------------------------------------------
// Per-node fused epilogue: GAT gather (recompute w) + HG gather + ELU.
// ---------------------------------------------------------------------------
__global__ __launch_bounds__(256, 8) void k_out(
    const int* __restrict__ start_g, const int* __restrict__ src_sorted,
    const int* __restrict__ start_v, const int* __restrict__ e_sorted,
    const float* __restrict__ ssrc, const float* __restrict__ sdst,
    const unsigned short* __restrict__ Xp_bf, const unsigned short* __restrict__ He_bf,
    const float* __restrict__ dvis, float* __restrict__ out, int N)
{
    int lane = threadIdx.x & 63, grp = lane >> 3, gl = lane & 7;
    int n = (blockIdx.x * 256 + threadIdx.x) >> 6;
    if (n >= N) return;

    float sd = sdst[n];
    int gs = start_g[n], ge = start_g[n + 1];
    float g[8] = {0.f, 0.f, 0.f, 0.f, 0.f, 0.f, 0.f, 0.f};
    float wsum = 0.f;
    for (int i = gs + grp; i < ge; i += 8) {
        int s = src_sorted[i];
        float sc = ssrc[s] + sd;
        sc = sc > 0.f ? sc : 0.2f * sc;
        float w = __expf(sc);
        wsum += w;
        uint4 r = *(const uint4*)(Xp_bf + (size_t)s * DD + gl * 8);
        g[0] = fmaf(w, bflo(r.x), g[0]); g[1] = fmaf(w, bfhi(r.x), g[1]);
        g[2] = fmaf(w, bflo(r.y), g[2]); g[3] = fmaf(w, bfhi(r.y), g[3]);
        g[4] = fmaf(w, bflo(r.z), g[4]); g[5] = fmaf(w, bfhi(r.z), g[5]);
        g[6] = fmaf(w, bflo(r.w), g[6]); g[7] = fmaf(w, bfhi(r.w), g[7]);
    }
    int vs = start_v[n], ve = start_v[n + 1];
    float h[8] = {0.f, 0.f, 0.f, 0.f, 0.f, 0.f, 0.f, 0.f};
    for (int i = vs + grp; i < ve; i += 8) {
        int e = e_sorted[i];
        uint4 r = *(const uint4*)(He_bf + (size_t)e * DD + gl * 8);
        h[0] += bflo(r.x); h[1] += bfhi(r.x);
        h[2] += bflo(r.y); h[3] += bfhi(r.y);
        h[4] += bflo(r.z); h[5] += bfhi(r.z);
        h[6] += bflo(r.w); h[7] += bfhi(r.w);
    }
    #pragma unroll
    for (int off = 8; off < 64; off <<= 1) {
        #pragma unroll
        for (int j = 0; j < 8; ++j) {
            g[j] += __shfl_xor(g[j], off, 64);
            h[j] += __shfl_xor(h[j], off, 64);
        }
        wsum += __shfl_xor(wsum, off, 64);
    }
    if (grp == 0) {
        float winv = (ge > gs) ? 1.0f / wsum : 0.f;
        float dvn = dvis[n];
        float o[8];
        #pragma unroll
        for (int j = 0; j < 8; ++j) {
            float x = 0.5f * (g[j] * winv + dvn * h[j]);
            o[j] = x > 0.f ? x : expm1f(x);
        }
        float* op = out + (size_t)n * DD + gl * 8;
        *(float4*)op       = make_float4(o[0], o[1], o[2], o[3]);
        *(float4*)(op + 4) = make_float4(o[4], o[5], o[6], o[7]);
    }
}

extern "C" void kernel_launch(void* const* d_in, const int* in_sizes, int n_in,
                              void* d_out, int out_size, void* d_ws, size_t ws_size,
                              hipStream_t stream)
{
    const float* X     = (const float*)d_in[0];
    const float* W     = (const float*)d_in[1];
    const float* bias  = (const float*)d_in[2];
    const float* a_src = (const float*)d_in[3];
    const float* a_dst = (const float*)d_in[4];
    const int* e_src   = (const int*)d_in[5];
    const int* e_dst   = (const int*)d_in[6];
    const int* inc_v   = (const int*)d_in[7];
    const int* inc_e   = (const int*)d_in[8];
    float* out = (float*)d_out;

    const int N = in_sizes[0] / DD;   // 50000
    const int E = in_sizes[5];        // 800000
    const int P = in_sizes[7];        // 200000
    const int M = 10000;
    const int Bg = (N + 511) >> 9, Bie = (M + 255) >> 8, Biv = Bg;

    char* p = (char*)d_ws;
    unsigned short* Xp_bf = (unsigned short*)p; p += (size_t)N * DD * 2;
    unsigned short* He_bf = (unsigned short*)p; p += (size_t)M * DD * 2;
    int2* pg  = (int2*)p; p += (size_t)E * 8;
    int2* pie = (int2*)p; p += (size_t)P * 8;
    int2* piv = (int2*)p; p += (size_t)P * 8;
    int* src_sorted = (int*)p; p += (size_t)E * 4;
    int* v_sorted   = (int*)p; p += (size_t)P * 4;
    int* e_sorted   = (int*)p; p += (size_t)P * 4;
    float* ssrc = (float*)p; p += (size_t)N * 4;
    float* sdst = (float*)p; p += (size_t)N * 4;
    float* dvis = (float*)p; p += (size_t)N * 4;
    float* dein = (float*)p; p += (size_t)M * 4;
    int* start_g = (int*)p; p += (size_t)(N + 1) * 4;
    int* start_v = (int*)p; p += (size_t)(N + 1) * 4;
    int* start_e = (int*)p; p += (size_t)(M + 1) * 4;
    int* hist_g  = (int*)p; p += (size_t)(Bg * 256 + 1) * 4;
    int* hist_ie = (int*)p; p += (size_t)(Bie * 128 + 1) * 4;
    int* hist_iv = (int*)p; p += (size_t)(Biv * 128 + 1) * 4;

    k_gemm<<<196, 256, 0, stream>>>(X, W, bias, a_src, a_dst, Xp_bf, ssrc, sdst, N);
    k_count<<<512, 256, 0, stream>>>(e_dst, inc_e, inc_v, hist_g, hist_ie, hist_iv,
                                     E, P, N, M);
    k_scan3<<<3, 1024, 0, stream>>>(hist_g, Bg * 256, hist_ie, Bie * 128,
                                    hist_iv, Biv * 128);
    k_scat<<<512, 256, 0, stream>>>(e_dst, e_src, inc_e, inc_v,
                                    hist_g, hist_ie, hist_iv, pg, pie, piv,
                                    E, P, N, M);
    k_fine<<<Bg + Bie + Biv, 256, 0, stream>>>(hist_g, hist_ie, hist_iv, pg, pie, piv,
                                               src_sorted, v_sorted, e_sorted,
                                               start_g, start_e, start_v,
                                               dein, dvis, N, M);
    k_he<<<(M * DD + 255) / 256, 256, 0, stream>>>(start_e, v_sorted, Xp_bf, dvis,
                                                   dein, He_bf, M);
    k_out<<<(N * DD + 255) / 256, 256, 0, stream>>>(start_g, src_sorted, start_v,
                                                    e_sorted, ssrc, sdst, Xp_bf,
                                                    He_bf, dvis, out, N);
}

// Round 6
// 108.525 us; speedup vs baseline: 3.7665x; 1.0807x over previous
//
#include <hip/hip_runtime.h>
#include <math.h>

#define DD 64

typedef __attribute__((ext_vector_type(8))) short bf16x8;
typedef __attribute__((ext_vector_type(4))) float f32x4;

__device__ __forceinline__ unsigned short f2bf(float x) {
    unsigned int u = __float_as_uint(x);
    u += 0x7fffu + ((u >> 16) & 1u);      // round-to-nearest-even
    return (unsigned short)(u >> 16);
}
__device__ __forceinline__ float bflo(unsigned int u) { return __uint_as_float(u << 16); }
__device__ __forceinline__ float bfhi(unsigned int u) { return __uint_as_float(u & 0xffff0000u); }

// ---------------------------------------------------------------------------
// Fused: blocks [0,GB): MFMA GEMM (Xp_bf, s_src, s_dst).
//        blocks [GB, GB+512): multisplit coarse histograms.
// ---------------------------------------------------------------------------
#define GEMM_BLOCKS 196

__global__ __launch_bounds__(256) void k_gemm_count(
    const float* __restrict__ X, const float* __restrict__ W,
    const float* __restrict__ bias, const float* __restrict__ a_src,
    const float* __restrict__ a_dst, unsigned short* __restrict__ Xp_bf,
    float* __restrict__ s_src, float* __restrict__ s_dst,
    const int* __restrict__ e_dst, const int* __restrict__ inc_e,
    const int* __restrict__ inc_v, int* __restrict__ hist_g,
    int* __restrict__ hist_ie, int* __restrict__ hist_iv,
    int N, int E, int P, int M)
{
    if (blockIdx.x >= GEMM_BLOCKS) {
        // ---------------- histogram branch ----------------
        __shared__ int cnt[128];
        int b = blockIdx.x - GEMM_BLOCKS;
        const int* key; int n, B, SH, nblk, blk; int* hist;
        if (b < 256)      { key = e_dst; n = E; B = (N + 511) >> 9; SH = 9; nblk = 256; blk = b;       hist = hist_g;  }
        else if (b < 384) { key = inc_e; n = P; B = (M + 255) >> 8; SH = 8; nblk = 128; blk = b - 256; hist = hist_ie; }
        else              { key = inc_v; n = P; B = (N + 511) >> 9; SH = 9; nblk = 128; blk = b - 384; hist = hist_iv; }
        for (int i = threadIdx.x; i < B; i += 256) cnt[i] = 0;
        __syncthreads();
        int chunk = (n + nblk - 1) / nblk;
        int s = blk * chunk, e = min(n, s + chunk);
        for (int i = s + threadIdx.x; i < e; i += 256)
            atomicAdd(&cnt[key[i] >> SH], 1);
        __syncthreads();
        for (int i = threadIdx.x; i < B; i += 256)
            hist[i * nblk + blk] = cnt[i];
        return;
    }
    // ---------------- GEMM branch ----------------
    int t = threadIdx.x;
    int lane = t & 63;
    int col = lane & 15;
    int kq  = lane >> 4;
    int rowbase = kq * 4;

    bf16x8 bfrag[4][2];
    float bj[4], asr[4], adr[4];
    #pragma unroll
    for (int jt = 0; jt < 4; ++jt) {
        int j = jt * 16 + col;
        #pragma unroll
        for (int ks = 0; ks < 2; ++ks) {
            const float* wp = W + j * DD + ks * 32 + kq * 8;
            float4 w0 = *(const float4*)wp;
            float4 w1 = *(const float4*)(wp + 4);
            bf16x8 bb;
            bb[0] = (short)f2bf(w0.x); bb[1] = (short)f2bf(w0.y);
            bb[2] = (short)f2bf(w0.z); bb[3] = (short)f2bf(w0.w);
            bb[4] = (short)f2bf(w1.x); bb[5] = (short)f2bf(w1.y);
            bb[6] = (short)f2bf(w1.z); bb[7] = (short)f2bf(w1.w);
            bfrag[jt][ks] = bb;
        }
        bj[jt]  = bias[j];
        asr[jt] = a_src[j];
        adr[jt] = a_dst[j];
    }

    int wave  = (blockIdx.x * 256 + t) >> 6;
    int nwave = (GEMM_BLOCKS * 256) >> 6;
    int ntiles = (N + 15) >> 4;
    for (int tile = wave; tile < ntiles; tile += nwave) {
        int r0 = tile * 16;
        int rl = r0 + col;
        if (rl >= N) rl = N - 1;
        const float* xp = X + (size_t)rl * DD + kq * 8;
        float4 x0 = *(const float4*)xp;
        float4 x1 = *(const float4*)(xp + 4);
        float4 x2 = *(const float4*)(xp + 32);
        float4 x3 = *(const float4*)(xp + 36);
        bf16x8 a0, a1;
        a0[0] = (short)f2bf(x0.x); a0[1] = (short)f2bf(x0.y);
        a0[2] = (short)f2bf(x0.z); a0[3] = (short)f2bf(x0.w);
        a0[4] = (short)f2bf(x1.x); a0[5] = (short)f2bf(x1.y);
        a0[6] = (short)f2bf(x1.z); a0[7] = (short)f2bf(x1.w);
        a1[0] = (short)f2bf(x2.x); a1[1] = (short)f2bf(x2.y);
        a1[2] = (short)f2bf(x2.z); a1[3] = (short)f2bf(x2.w);
        a1[4] = (short)f2bf(x3.x); a1[5] = (short)f2bf(x3.y);
        a1[6] = (short)f2bf(x3.z); a1[7] = (short)f2bf(x3.w);

        f32x4 acc[4];
        #pragma unroll
        for (int jt = 0; jt < 4; ++jt) {
            f32x4 c = {bj[jt], bj[jt], bj[jt], bj[jt]};
            c = __builtin_amdgcn_mfma_f32_16x16x32_bf16(a0, bfrag[jt][0], c, 0, 0, 0);
            c = __builtin_amdgcn_mfma_f32_16x16x32_bf16(a1, bfrag[jt][1], c, 0, 0, 0);
            acc[jt] = c;
        }

        int orow = r0 + rowbase;
        #pragma unroll
        for (int jt = 0; jt < 4; ++jt) {
            #pragma unroll
            for (int r = 0; r < 4; ++r) {
                int rr = orow + r;
                if (rr < N)
                    Xp_bf[(size_t)rr * DD + jt * 16 + col] = f2bf(acc[jt][r]);
            }
        }

        float vs[4], vd[4];
        #pragma unroll
        for (int r = 0; r < 4; ++r) {
            vs[r] = acc[0][r] * asr[0] + acc[1][r] * asr[1]
                  + acc[2][r] * asr[2] + acc[3][r] * asr[3];
            vd[r] = acc[0][r] * adr[0] + acc[1][r] * adr[1]
                  + acc[2][r] * adr[2] + acc[3][r] * adr[3];
        }
        #pragma unroll
        for (int off = 1; off < 16; off <<= 1) {
            #pragma unroll
            for (int r = 0; r < 4; ++r) {
                vs[r] += __shfl_xor(vs[r], off, 64);
                vd[r] += __shfl_xor(vd[r], off, 64);
            }
        }
        if (col == 0) {
            #pragma unroll
            for (int r = 0; r < 4; ++r) {
                int rr = orow + r;
                if (rr < N) { s_src[rr] = vs[r]; s_dst[rr] = vd[r]; }
            }
        }
    }
}

// ---------------------------------------------------------------------------
// In-place exclusive scan (one block, 1024 threads, 4 elems/thread).
// ---------------------------------------------------------------------------
__device__ void block_scan4(int* a, int len)
{
    __shared__ int wtot[16];
    __shared__ int carry_s;
    int tid = threadIdx.x, lane = tid & 63, wid = tid >> 6;
    if (tid == 0) carry_s = 0;
    __syncthreads();
    for (int base = 0; base < len; base += 4096) {
        int i0 = base + tid * 4;
        int v[4];
        #pragma unroll
        for (int k = 0; k < 4; ++k) { int i = i0 + k; v[k] = (i < len) ? a[i] : 0; }
        int s = v[0] + v[1] + v[2] + v[3];
        int incl = s;
        #pragma unroll
        for (int off = 1; off < 64; off <<= 1) {
            int t = __shfl_up(incl, off, 64);
            if (lane >= off) incl += t;
        }
        if (lane == 63) wtot[wid] = incl;
        __syncthreads();
        int carry = carry_s;
        int woff = 0;
        for (int wj = 0; wj < wid; ++wj) woff += wtot[wj];
        int excl = carry + woff + incl - s;
        int run = excl;
        #pragma unroll
        for (int k = 0; k < 4; ++k) { int i = i0 + k; if (i < len) a[i] = run; run += v[k]; }
        __syncthreads();
        if (tid == 1023) carry_s = run;
        __syncthreads();
    }
    if (tid == 0) a[len] = carry_s;
}

__global__ __launch_bounds__(1024) void k_scan3(
    int* h0, int l0, int* h1, int l1, int* h2, int l2)
{
    if (blockIdx.x == 0)      block_scan4(h0, l0);
    else if (blockIdx.x == 1) block_scan4(h1, l1);
    else                      block_scan4(h2, l2);
}

// ---------------------------------------------------------------------------
// Multisplit pass 2: scatter PACKED (fine_key | payload<<SH) into
// per-(block,bucket) regions. 4 B per item.
// ---------------------------------------------------------------------------
__global__ __launch_bounds__(256) void k_scat(
    const int* __restrict__ e_dst, const int* __restrict__ e_src,
    const int* __restrict__ inc_e, const int* __restrict__ inc_v,
    const int* __restrict__ hist_g, const int* __restrict__ hist_ie,
    const int* __restrict__ hist_iv,
    unsigned int* __restrict__ pg, unsigned int* __restrict__ pie,
    unsigned int* __restrict__ piv,
    int E, int P, int N, int M)
{
    __shared__ int cur[128];
    int b = blockIdx.x;
    const int *key, *pay, *base; unsigned int* out;
    int n, B, SH, nblk, blk;
    if (b < 256)      { key = e_dst; pay = e_src; n = E; B = (N + 511) >> 9; SH = 9; nblk = 256; blk = b;       base = hist_g;  out = pg;  }
    else if (b < 384) { key = inc_e; pay = inc_v; n = P; B = (M + 255) >> 8; SH = 8; nblk = 128; blk = b - 256; base = hist_ie; out = pie; }
    else              { key = inc_v; pay = inc_e; n = P; B = (N + 511) >> 9; SH = 9; nblk = 128; blk = b - 384; base = hist_iv; out = piv; }
    for (int i = threadIdx.x; i < B; i += 256) cur[i] = base[i * nblk + blk];
    __syncthreads();
    int chunk = (n + nblk - 1) / nblk;
    int s = blk * chunk, e = min(n, s + chunk);
    int mask = (1 << SH) - 1;
    for (int i = s + threadIdx.x; i < e; i += 256) {
        int k = key[i];
        int pos = atomicAdd(&cur[k >> SH], 1);
        out[pos] = (unsigned int)(k & mask) | ((unsigned int)pay[i] << SH);
    }
}

// ---------------------------------------------------------------------------
// Multisplit pass 3: per-bucket fine counting sort in LDS (packed input).
// ---------------------------------------------------------------------------
__global__ __launch_bounds__(256) void k_fine(
    const int* __restrict__ hist_g, const int* __restrict__ hist_ie,
    const int* __restrict__ hist_iv,
    const unsigned int* __restrict__ pg, const unsigned int* __restrict__ pie,
    const unsigned int* __restrict__ piv,
    int* __restrict__ src_sorted, int* __restrict__ v_sorted,
    int* __restrict__ e_sorted,
    int* __restrict__ start_g, int* __restrict__ start_e,
    int* __restrict__ start_v,
    float* __restrict__ dein, float* __restrict__ dvis, int N, int M)
{
    __shared__ int lh[513];
    __shared__ int lc[512];
    __shared__ int lwt[4];
    __shared__ int lout[10240];
    int Bg = (N + 511) >> 9, Bie = (M + 255) >> 8;
    int b = blockIdx.x, tid = threadIdx.x;
    const int* base; const unsigned int* pr; int* outp; int* startp; float* inv;
    int K, nblk, b0, NK, mode;
    if (b < Bg)            { base = hist_g;  pr = pg;  outp = src_sorted; startp = start_g; inv = nullptr; K = 512; nblk = 256; b0 = b;            NK = N; mode = 0; }
    else if (b < Bg + Bie) { base = hist_ie; pr = pie; outp = v_sorted;   startp = start_e; inv = dein;    K = 256; nblk = 128; b0 = b - Bg;       NK = M; mode = 2; }
    else                   { base = hist_iv; pr = piv; outp = e_sorted;   startp = start_v; inv = dvis;    K = 512; nblk = 128; b0 = b - Bg - Bie; NK = N; mode = 1; }
    int SHF = (K == 512) ? 9 : 8;

    int pbase = base[b0 * nblk], pend = base[(b0 + 1) * nblk];
    int cnt = pend - pbase;
    for (int i = tid; i < K; i += 256) { lh[i] = 0; lc[i] = 0; }
    __syncthreads();
    for (int i = tid; i < cnt; i += 256)
        atomicAdd(&lh[pr[pbase + i] & (K - 1)], 1);
    __syncthreads();

    int per = K >> 8;
    int i0 = tid * per;
    int a0 = lh[i0], a1 = (per == 2) ? lh[i0 + 1] : 0;
    int ssum = a0 + a1;
    int lane = tid & 63, wid = tid >> 6;
    int incl = ssum;
    #pragma unroll
    for (int off = 1; off < 64; off <<= 1) {
        int t = __shfl_up(incl, off, 64);
        if (lane >= off) incl += t;
    }
    if (lane == 63) lwt[wid] = incl;
    __syncthreads();
    int woff = 0;
    for (int wj = 0; wj < wid; ++wj) woff += lwt[wj];
    int excl = woff + incl - ssum;
    lh[i0] = excl;
    if (per == 2) lh[i0 + 1] = excl + a0;
    if (tid == 255) lh[K] = excl + ssum;
    __syncthreads();

    for (int i = tid; i < cnt; i += 256) {
        unsigned int q = pr[pbase + i];
        int kl = q & (K - 1);
        int pos = lh[kl] + atomicAdd(&lc[kl], 1);
        lout[pos < 10240 ? pos : 10239] = (int)(q >> SHF);
    }
    __syncthreads();
    for (int i = tid; i < cnt; i += 256)
        outp[pbase + i] = lout[i];
    for (int k = tid; k < K; k += 256) {
        int node = b0 * K + k;
        if (node < NK) {
            startp[node] = pbase + lh[k];
            if (mode) {
                int d = lh[k + 1] - lh[k];
                inv[node] = d > 0 ? (mode == 1 ? rsqrtf((float)d) : 1.0f / (float)d) : 0.0f;
            }
        }
    }
    int Bj = (NK + K - 1) / K;
    if (tid == 0 && b0 == Bj - 1) startp[NK] = pend;
}

// ---------------------------------------------------------------------------
// He_bf[e][:] = bf16( dein[e] * sum_v Xp[v][:]*dvis[v] ).  Unroll-2 MLP.
// ---------------------------------------------------------------------------
__global__ __launch_bounds__(256, 8) void k_he(
    const int* __restrict__ start_e, const int* __restrict__ v_sorted,
    const unsigned short* __restrict__ Xp_bf, const float* __restrict__ dvis,
    const float* __restrict__ dein, unsigned short* __restrict__ He_bf, int M)
{
    int lane = threadIdx.x & 63, grp = lane >> 3, gl = lane & 7;
    int e = (blockIdx.x * 256 + threadIdx.x) >> 6;
    if (e >= M) return;
    int s = start_e[e], t = start_e[e + 1];
    float a[8] = {0.f, 0.f, 0.f, 0.f, 0.f, 0.f, 0.f, 0.f};
    int i = s + grp;
    for (; i + 8 < t; i += 16) {
        int v0 = v_sorted[i], v1 = v_sorted[i + 8];
        uint4 r0 = *(const uint4*)(Xp_bf + (size_t)v0 * DD + gl * 8);
        uint4 r1 = *(const uint4*)(Xp_bf + (size_t)v1 * DD + gl * 8);
        float d0 = dvis[v0], d1 = dvis[v1];
        a[0] = fmaf(d0, bflo(r0.x), a[0]); a[1] = fmaf(d0, bfhi(r0.x), a[1]);
        a[2] = fmaf(d0, bflo(r0.y), a[2]); a[3] = fmaf(d0, bfhi(r0.y), a[3]);
        a[4] = fmaf(d0, bflo(r0.z), a[4]); a[5] = fmaf(d0, bfhi(r0.z), a[5]);
        a[6] = fmaf(d0, bflo(r0.w), a[6]); a[7] = fmaf(d0, bfhi(r0.w), a[7]);
        a[0] = fmaf(d1, bflo(r1.x), a[0]); a[1] = fmaf(d1, bfhi(r1.x), a[1]);
        a[2] = fmaf(d1, bflo(r1.y), a[2]); a[3] = fmaf(d1, bfhi(r1.y), a[3]);
        a[4] = fmaf(d1, bflo(r1.z), a[4]); a[5] = fmaf(d1, bfhi(r1.z), a[5]);
        a[6] = fmaf(d1, bflo(r1.w), a[6]); a[7] = fmaf(d1, bfhi(r1.w), a[7]);
    }
    if (i < t) {
        int v0 = v_sorted[i];
        uint4 r0 = *(const uint4*)(Xp_bf + (size_t)v0 * DD + gl * 8);
        float d0 = dvis[v0];
        a[0] = fmaf(d0, bflo(r0.x), a[0]); a[1] = fmaf(d0, bfhi(r0.x), a[1]);
        a[2] = fmaf(d0, bflo(r0.y), a[2]); a[3] = fmaf(d0, bfhi(r0.y), a[3]);
        a[4] = fmaf(d0, bflo(r0.z), a[4]); a[5] = fmaf(d0, bfhi(r0.z), a[5]);
        a[6] = fmaf(d0, bflo(r0.w), a[6]); a[7] = fmaf(d0, bfhi(r0.w), a[7]);
    }
    #pragma unroll
    for (int off = 8; off < 64; off <<= 1) {
        #pragma unroll
        for (int j = 0; j < 8; ++j) a[j] += __shfl_xor(a[j], off, 64);
    }
    if (grp == 0) {
        float din = dein[e];
        uint4 o;
        o.x = (unsigned)f2bf(a[0] * din) | ((unsigned)f2bf(a[1] * din) << 16);
        o.y = (unsigned)f2bf(a[2] * din) | ((unsigned)f2bf(a[3] * din) << 16);
        o.z = (unsigned)f2bf(a[4] * din) | ((unsigned)f2bf(a[5] * din) << 16);
        o.w = (unsigned)f2bf(a[6] * din) | ((unsigned)f2bf(a[7] * din) << 16);
        *(uint4*)(He_bf + (size_t)e * DD + gl * 8) = o;
    }
}

// ---------------------------------------------------------------------------
// Per-node fused epilogue. Unroll-2 MLP in both gather loops.
// ---------------------------------------------------------------------------
__global__ __launch_bounds__(256, 8) void k_out(
    const int* __restrict__ start_g, const int* __restrict__ src_sorted,
    const int* __restrict__ start_v, const int* __restrict__ e_sorted,
    const float* __restrict__ ssrc, const float* __restrict__ sdst,
    const unsigned short* __restrict__ Xp_bf, const unsigned short* __restrict__ He_bf,
    const float* __restrict__ dvis, float* __restrict__ out, int N)
{
    int lane = threadIdx.x & 63, grp = lane >> 3, gl = lane & 7;
    int n = (blockIdx.x * 256 + threadIdx.x) >> 6;
    if (n >= N) return;

    float sd = sdst[n];
    int gs = start_g[n], ge = start_g[n + 1];
    float g[8] = {0.f, 0.f, 0.f, 0.f, 0.f, 0.f, 0.f, 0.f};
    float wsum = 0.f;
    int i = gs + grp;
    for (; i + 8 < ge; i += 16) {
        int s0 = src_sorted[i], s1 = src_sorted[i + 8];
        uint4 r0 = *(const uint4*)(Xp_bf + (size_t)s0 * DD + gl * 8);
        uint4 r1 = *(const uint4*)(Xp_bf + (size_t)s1 * DD + gl * 8);
        float sc0 = ssrc[s0] + sd; sc0 = sc0 > 0.f ? sc0 : 0.2f * sc0;
        float sc1 = ssrc[s1] + sd; sc1 = sc1 > 0.f ? sc1 : 0.2f * sc1;
        float w0 = __expf(sc0), w1 = __expf(sc1);
        wsum += w0 + w1;
        g[0] = fmaf(w0, bflo(r0.x), g[0]); g[1] = fmaf(w0, bfhi(r0.x), g[1]);
        g[2] = fmaf(w0, bflo(r0.y), g[2]); g[3] = fmaf(w0, bfhi(r0.y), g[3]);
        g[4] = fmaf(w0, bflo(r0.z), g[4]); g[5] = fmaf(w0, bfhi(r0.z), g[5]);
        g[6] = fmaf(w0, bflo(r0.w), g[6]); g[7] = fmaf(w0, bfhi(r0.w), g[7]);
        g[0] = fmaf(w1, bflo(r1.x), g[0]); g[1] = fmaf(w1, bfhi(r1.x), g[1]);
        g[2] = fmaf(w1, bflo(r1.y), g[2]); g[3] = fmaf(w1, bfhi(r1.y), g[3]);
        g[4] = fmaf(w1, bflo(r1.z), g[4]); g[5] = fmaf(w1, bfhi(r1.z), g[5]);
        g[6] = fmaf(w1, bflo(r1.w), g[6]); g[7] = fmaf(w1, bfhi(r1.w), g[7]);
    }
    if (i < ge) {
        int s0 = src_sorted[i];
        uint4 r0 = *(const uint4*)(Xp_bf + (size_t)s0 * DD + gl * 8);
        float sc0 = ssrc[s0] + sd; sc0 = sc0 > 0.f ? sc0 : 0.2f * sc0;
        float w0 = __expf(sc0);
        wsum += w0;
        g[0] = fmaf(w0, bflo(r0.x), g[0]); g[1] = fmaf(w0, bfhi(r0.x), g[1]);
        g[2] = fmaf(w0, bflo(r0.y), g[2]); g[3] = fmaf(w0, bfhi(r0.y), g[3]);
        g[4] = fmaf(w0, bflo(r0.z), g[4]); g[5] = fmaf(w0, bfhi(r0.z), g[5]);
        g[6] = fmaf(w0, bflo(r0.w), g[6]); g[7] = fmaf(w0, bfhi(r0.w), g[7]);
    }
    int vs = start_v[n], ve = start_v[n + 1];
    float h[8] = {0.f, 0.f, 0.f, 0.f, 0.f, 0.f, 0.f, 0.f};
    i = vs + grp;
    for (; i + 8 < ve; i += 16) {
        int e0 = e_sorted[i], e1 = e_sorted[i + 8];
        uint4 r0 = *(const uint4*)(He_bf + (size_t)e0 * DD + gl * 8);
        uint4 r1 = *(const uint4*)(He_bf + (size_t)e1 * DD + gl * 8);
        h[0] += bflo(r0.x) + bflo(r1.x); h[1] += bfhi(r0.x) + bfhi(r1.x);
        h[2] += bflo(r0.y) + bflo(r1.y); h[3] += bfhi(r0.y) + bfhi(r1.y);
        h[4] += bflo(r0.z) + bflo(r1.z); h[5] += bfhi(r0.z) + bfhi(r1.z);
        h[6] += bflo(r0.w) + bflo(r1.w); h[7] += bfhi(r0.w) + bfhi(r1.w);
    }
    if (i < ve) {
        int e0 = e_sorted[i];
        uint4 r0 = *(const uint4*)(He_bf + (size_t)e0 * DD + gl * 8);
        h[0] += bflo(r0.x); h[1] += bfhi(r0.x);
        h[2] += bflo(r0.y); h[3] += bfhi(r0.y);
        h[4] += bflo(r0.z); h[5] += bfhi(r0.z);
        h[6] += bflo(r0.w); h[7] += bfhi(r0.w);
    }
    #pragma unroll
    for (int off = 8; off < 64; off <<= 1) {
        #pragma unroll
        for (int j = 0; j < 8; ++j) {
            g[j] += __shfl_xor(g[j], off, 64);
            h[j] += __shfl_xor(h[j], off, 64);
        }
        wsum += __shfl_xor(wsum, off, 64);
    }
    if (grp == 0) {
        float winv = (ge > gs) ? 1.0f / wsum : 0.f;
        float dvn = dvis[n];
        float o[8];
        #pragma unroll
        for (int j = 0; j < 8; ++j) {
            float x = 0.5f * (g[j] * winv + dvn * h[j]);
            o[j] = x > 0.f ? x : expm1f(x);
        }
        float* op = out + (size_t)n * DD + gl * 8;
        *(float4*)op       = make_float4(o[0], o[1], o[2], o[3]);
        *(float4*)(op + 4) = make_float4(o[4], o[5], o[6], o[7]);
    }
}

extern "C" void kernel_launch(void* const* d_in, const int* in_sizes, int n_in,
                              void* d_out, int out_size, void* d_ws, size_t ws_size,
                              hipStream_t stream)
{
    const float* X     = (const float*)d_in[0];
    const float* W     = (const float*)d_in[1];
    const float* bias  = (const float*)d_in[2];
    const float* a_src = (const float*)d_in[3];
    const float* a_dst = (const float*)d_in[4];
    const int* e_src   = (const int*)d_in[5];
    const int* e_dst   = (const int*)d_in[6];
    const int* inc_v   = (const int*)d_in[7];
    const int* inc_e   = (const int*)d_in[8];
    float* out = (float*)d_out;

    const int N = in_sizes[0] / DD;   // 50000
    const int E = in_sizes[5];        // 800000
    const int P = in_sizes[7];        // 200000
    const int M = 10000;
    const int Bg = (N + 511) >> 9, Bie = (M + 255) >> 8, Biv = Bg;

    char* p = (char*)d_ws;
    unsigned short* Xp_bf = (unsigned short*)p; p += (size_t)N * DD * 2;
    unsigned short* He_bf = (unsigned short*)p; p += (size_t)M * DD * 2;
    unsigned int* pg  = (unsigned int*)p; p += (size_t)E * 4;
    unsigned int* pie = (unsigned int*)p; p += (size_t)P * 4;
    unsigned int* piv = (unsigned int*)p; p += (size_t)P * 4;
    int* src_sorted = (int*)p; p += (size_t)E * 4;
    int* v_sorted   = (int*)p; p += (size_t)P * 4;
    int* e_sorted   = (int*)p; p += (size_t)P * 4;
    float* ssrc = (float*)p; p += (size_t)N * 4;
    float* sdst = (float*)p; p += (size_t)N * 4;
    float* dvis = (float*)p; p += (size_t)N * 4;
    float* dein = (float*)p; p += (size_t)M * 4;
    int* start_g = (int*)p; p += (size_t)(N + 1) * 4;
    int* start_v = (int*)p; p += (size_t)(N + 1) * 4;
    int* start_e = (int*)p; p += (size_t)(M + 1) * 4;
    int* hist_g  = (int*)p; p += (size_t)(Bg * 256 + 1) * 4;
    int* hist_ie = (int*)p; p += (size_t)(Bie * 128 + 1) * 4;
    int* hist_iv = (int*)p; p += (size_t)(Biv * 128 + 1) * 4;

    k_gemm_count<<<GEMM_BLOCKS + 512, 256, 0, stream>>>(
        X, W, bias, a_src, a_dst, Xp_bf, ssrc, sdst,
        e_dst, inc_e, inc_v, hist_g, hist_ie, hist_iv, N, E, P, M);
    k_scan3<<<3, 1024, 0, stream>>>(hist_g, Bg * 256, hist_ie, Bie * 128,
                                    hist_iv, Biv * 128);
    k_scat<<<512, 256, 0, stream>>>(e_dst, e_src, inc_e, inc_v,
                                    hist_g, hist_ie, hist_iv, pg, pie, piv,
                                    E, P, N, M);
    k_fine<<<Bg + Bie + Biv, 256, 0, stream>>>(hist_g, hist_ie, hist_iv, pg, pie, piv,
                                               src_sorted, v_sorted, e_sorted,
                                               start_g, start_e, start_v,
                                               dein, dvis, N, M);
    k_he<<<(M * DD + 255) / 256, 256, 0, stream>>>(start_e, v_sorted, Xp_bf, dvis,
                                                   dein, He_bf, M);
    k_out<<<(N * DD + 255) / 256, 256, 0, stream>>>(start_g, src_sorted, start_v,
                                                    e_sorted, ssrc, sdst, Xp_bf,
                                                    He_bf, dvis, out, N);
}